// Round 1
// baseline (325.362 us; speedup 1.0000x reference)
//
#include <hip/hip_runtime.h>
#include <stdint.h>

#define N_PTS 2048
#define NK 5
#define TOPK 512
#define CAP_MAX 262144u

// frozen arithmetic (r9-verified bit-exact vs np oracle):
//   d2 = fma(dz,dz, fma(dx,dx, dy*dy)); d = sqrt(max(d2,0))
//   q = fdiv(diff*diff, 0.01f); temp = max(1-q,0); v = (L*temp)*A
// tie rule: value desc, flat idx asc (key (vb<<32)|~idx descending)
// rejection bounds (exact under rounding, temp<=1, A<1):
//   v <= fmul_rn(Lsr,temp) <= Lsr

// ws layout (bytes):
//      0  src_ne_idx   int[10240]    (40960)
//  40960  src_ne_dist  f32[10240]    (40960)
//  81920  ref_ne_idx   int[10240]    (40960)
// 122880  ref_ne_dist  f32[10240]    (40960)
// 163840  rowmax       uint[2048]    (8192)
// 172032  counters     uint[8]       (32)   [0]=cand_count [3]=T
// 172064  cand         uint64[cap]
#define OFF_SIDX   0
#define OFF_SDIST  40960
#define OFF_RIDX   81920
#define OFF_RDIST  122880
#define OFF_RMAX   163840
#define OFF_CNT    172032
#define OFF_CAND   172064

__device__ __forceinline__ unsigned long long shflxor64(unsigned long long v, int mask) {
  unsigned lo = (unsigned)v, hi = (unsigned)(v >> 32);
  lo = (unsigned)__shfl_xor((int)lo, mask);
  hi = (unsigned)__shfl_xor((int)hi, mask);
  return ((unsigned long long)hi << 32) | lo;
}

// ---------------- KNN: 512 blocks, 8 points/block, 32 lanes/point ------------
__global__ __launch_bounds__(256) void knn_kernel(
    const float* __restrict__ src, const float* __restrict__ ref,
    int* __restrict__ sidx, float* __restrict__ sdist,
    int* __restrict__ ridx, float* __restrict__ rdist) {
  __shared__ float sx[N_PTS], sy[N_PTS], sz[N_PTS];
  const bool is_ref = blockIdx.x >= 256;
  const float* pts = is_ref ? ref : src;
  int*   oidx  = is_ref ? ridx : sidx;
  float* odist = is_ref ? rdist : sdist;
  const int blk = is_ref ? (blockIdx.x - 256) : blockIdx.x;

  for (int t = threadIdx.x; t < N_PTS; t += 256) {
    sx[t] = pts[3 * t + 0];
    sy[t] = pts[3 * t + 1];
    sz[t] = pts[3 * t + 2];
  }
  __syncthreads();

  const int p = blk * 8 + (threadIdx.x >> 5);
  const int u = threadIdx.x & 31;
  const float px = sx[p], py = sy[p], pz = sz[p];

  unsigned long long best[6];
#pragma unroll
  for (int k = 0; k < 6; ++k) best[k] = ~0ull;

  for (int j = u; j < N_PTS; j += 32) {
    float dx = __fsub_rn(px, sx[j]);
    float dy = __fsub_rn(py, sy[j]);
    float dz = __fsub_rn(pz, sz[j]);
    float d2 = __builtin_fmaf(dz, dz,
                 __builtin_fmaf(dx, dx, __fmul_rn(dy, dy)));
    float d = __fsqrt_rn(fmaxf(d2, 0.0f));
    unsigned long long key = (((unsigned long long)__float_as_uint(d)) << 32)
                           | (unsigned)j;
    if (key < best[5]) {
      best[5] = key;
#pragma unroll
      for (int k = 5; k >= 1; --k)
        if (best[k] < best[k - 1]) {
          unsigned long long t = best[k]; best[k] = best[k - 1]; best[k - 1] = t;
        }
    }
  }

  int h = 0;
  unsigned long long win[6];
#pragma unroll
  for (int round = 0; round < 6; ++round) {
    unsigned long long my = (h < 6) ? best[h] : ~0ull;
    unsigned long long m = my;
#pragma unroll
    for (int msk = 16; msk >= 1; msk >>= 1) {
      unsigned long long o = shflxor64(m, msk);
      if (o < m) m = o;
    }
    win[round] = m;
    if (my == m) ++h;
  }

  if (u == 0) {
#pragma unroll
    for (int m = 1; m <= NK; ++m) {     // drop win[0] == self (d = 0)
      oidx[p * NK + m - 1]  = (int)(win[m] & 0xFFFFFFFFull);
      odist[p * NK + m - 1] = __uint_as_float((unsigned)(win[m] >> 32));
    }
  }
}

// ---------------- pass 1: exact per-row max via Lsr-first rejection ----------
// Multi-pass descending Lsr bands: pass p processes r iff lo[p] < Lsr <= lo[p-1]
// (exact partition of (0,inf); Lsr<=0 contributes v<=0, never raises s_max —
// identical to the old "Lsr <= smax(=0)" skip). High-Lsr columns are processed
// FIRST, so s_max is near-final after the first band and later bands reject
// almost everything via the dynamic Lsr<=smax test. Early exit: once
// smax >= lo[p], every unprocessed r has v <= Lsr <= lo[p] <= smax — whole
// remaining loop provably cannot change the max. Break decision is made
// uniform via tid-0 shared flag between two barriers (no divergent barriers).
// smax only ever holds exactly-computed v => rowmax exact => T identical =>
// output identical.
__global__ __launch_bounds__(256) void rowmax_kernel(
    const float* __restrict__ L,
    const int* __restrict__ sidx, const float* __restrict__ sdist,
    const int* __restrict__ ridx, const float* __restrict__ rdist,
    unsigned int* __restrict__ rowmax) {
  __shared__ float Lrow[N_PTS];
  __shared__ float sdsh[NK];
  __shared__ int   snsh[NK];
  __shared__ unsigned int s_max;
  __shared__ unsigned int s_done;
  const int s = blockIdx.x, tid = threadIdx.x;
  if (tid < NK) { snsh[tid] = sidx[s * NK + tid]; sdsh[tid] = sdist[s * NK + tid]; }
  if (tid == 0) s_max = 0;
  {
    const float4* src4 = (const float4*)(L + (size_t)s * N_PTS);
    float4* dst4 = (float4*)Lrow;
    for (int c = tid; c < N_PTS / 4; c += 256) dst4[c] = src4[c];
  }
  __syncthreads();

  float sd[NK];
#pragma unroll
  for (int i = 0; i < NK; ++i) sd[i] = sdsh[i];
  volatile unsigned int* vmax = &s_max;

  // L ~ U(0,1); rowmax is typically 0.97-0.99 (max over ~7K eligible L*A*temp
  // products), so nearly all rows break after 2-4 bands.
  const float bands[7] = {0.997f, 0.99f, 0.98f, 0.965f, 0.945f, 0.91f, 0.0f};
  float hi = 3.402823466e+38f;                 // band upper bound (exclusive-of-prev)
  for (int p = 0; p < 7; ++p) {
    const float lo = bands[p];
    for (int r = tid; r < N_PTS; r += 256) {
      float Lsr = Lrow[r];
      if (!(Lsr > lo) || Lsr > hi) continue;           // outside this band
      if (Lsr <= __uint_as_float(*vmax)) continue;     // v <= Lsr <= smax
      float rd[NK]; int rn[NK];
#pragma unroll
      for (int j = 0; j < NK; ++j) { rd[j] = rdist[r * NK + j]; rn[j] = ridx[r * NK + j]; }
      unsigned int lmax = *vmax;
#pragma unroll
      for (int i = 0; i < NK; ++i) {
        const float* __restrict__ Arow = L + (size_t)snsh[i] * N_PTS;
#pragma unroll
        for (int j = 0; j < NK; ++j) {
          float diff = __fsub_rn(sd[i], rd[j]);
          float dsq  = __fmul_rn(diff, diff);
          if (dsq >= 0.0101f) continue;                // temp provably 0
          float q    = __fdiv_rn(dsq, 0.01f);
          float temp = fmaxf(__fsub_rn(1.0f, q), 0.0f);
          if (temp <= 0.0f) continue;
          float ub   = __fmul_rn(Lsr, temp);           // frozen inner term
          if (__float_as_uint(ub) <= lmax && ub <= __uint_as_float(*vmax)) continue;
          float v = __fmul_rn(ub, Arow[rn[j]]);        // frozen chain
          unsigned int vb = __float_as_uint(v);
          if (v > 0.0f && vb > lmax) lmax = vb;
        }
      }
      if (lmax > *vmax) atomicMax(&s_max, lmax);
    }
    __syncthreads();
    if (tid == 0) s_done = (__uint_as_float(s_max) >= lo) ? 1u : 0u;
    __syncthreads();
    if (s_done) break;                                 // uniform across block
    hi = lo;
  }
  if (tid == 0) rowmax[s] = s_max;
}

// ---------------- threshold: T = 512th-largest row max; zero counter ---------
// count(v >= T) >= 512 guaranteed: each of the top-512 rows contributes >= 1.
__global__ __launch_bounds__(1024) void thresh_kernel(
    const unsigned int* __restrict__ rowmax, unsigned int* __restrict__ counters) {
  __shared__ unsigned int a[N_PTS];
  const int tid = threadIdx.x;
  for (int t = tid; t < N_PTS; t += 1024) a[t] = rowmax[t];
  __syncthreads();
  for (int k2 = 2; k2 <= N_PTS; k2 <<= 1) {
    for (int j2 = k2 >> 1; j2 > 0; j2 >>= 1) {
      for (int e = 0; e < N_PTS / 1024; ++e) {
        int i = tid + e * 1024;
        int pj = i ^ j2;
        if (pj > i) {
          bool blk = ((i & k2) == 0);
          unsigned int x = a[i], y = a[pj];
          if (blk ? (x < y) : (x > y)) { a[i] = y; a[pj] = x; }
        }
      }
      __syncthreads();
    }
  }
  if (tid == 0) {
    counters[3] = a[TOPK - 1];
    counters[0] = 0;
  }
}

// ---------------- pass 2: collect, static Lsr < T rejection ------------------
__global__ __launch_bounds__(256) void collect_kernel(
    const float* __restrict__ L,
    const int* __restrict__ sidx, const float* __restrict__ sdist,
    const int* __restrict__ ridx, const float* __restrict__ rdist,
    const unsigned int* __restrict__ rowmax,
    unsigned int* __restrict__ counters, uint64_t* __restrict__ cand,
    unsigned int cap) {
  __shared__ float Lrow[N_PTS];
  __shared__ float sdsh[NK];
  __shared__ int   snsh[NK];
  const int s = blockIdx.x, tid = threadIdx.x;
  const unsigned int T = counters[3];
  if (rowmax[s] < T) return;            // uniform: whole row can't contribute
  const float T_f = __uint_as_float(T);
  if (tid < NK) { snsh[tid] = sidx[s * NK + tid]; sdsh[tid] = sdist[s * NK + tid]; }
  {
    const float4* src4 = (const float4*)(L + (size_t)s * N_PTS);
    float4* dst4 = (float4*)Lrow;
    for (int c = tid; c < N_PTS / 4; c += 256) dst4[c] = src4[c];
  }
  __syncthreads();

  float sd[NK];
#pragma unroll
  for (int i = 0; i < NK; ++i) sd[i] = sdsh[i];

  for (int r = tid; r < N_PTS; r += 256) {
    float Lsr = Lrow[r];
    if (Lsr < T_f) continue;                             // v <= Lsr < T
    float rd[NK]; int rn[NK];
#pragma unroll
    for (int j = 0; j < NK; ++j) { rd[j] = rdist[r * NK + j]; rn[j] = ridx[r * NK + j]; }
#pragma unroll
    for (int i = 0; i < NK; ++i) {
      const float* __restrict__ Arow = L + (size_t)snsh[i] * N_PTS;
#pragma unroll
      for (int j = 0; j < NK; ++j) {
        float diff = __fsub_rn(sd[i], rd[j]);
        float dsq  = __fmul_rn(diff, diff);
        if (dsq >= 0.0101f) continue;
        float q    = __fdiv_rn(dsq, 0.01f);
        float temp = fmaxf(__fsub_rn(1.0f, q), 0.0f);
        if (temp <= 0.0f) continue;
        float ub   = __fmul_rn(Lsr, temp);
        if (ub < T_f) continue;                          // v <= ub < T
        float v = __fmul_rn(ub, Arow[rn[j]]);            // frozen chain
        unsigned int vb = __float_as_uint(v);
        if (v > 0.0f && vb >= T) {
          unsigned int pos = atomicAdd(&counters[0], 1u);
          if (pos < cap) {
            unsigned int idx = ((unsigned int)s * (unsigned int)N_PTS
                                + (unsigned int)r) * 25u
                             + (unsigned int)i * 5u + (unsigned int)j;
            cand[pos] = (((uint64_t)vb) << 32) | (uint64_t)((uint32_t)(~idx));
          }
        }
      }
    }
  }
}

// ---------------- exact top-512: byte radix-select + bitonic sort ------------
__global__ __launch_bounds__(1024) void select_kernel(
    const uint64_t* __restrict__ cand, const unsigned int* __restrict__ counters,
    const int* __restrict__ sidx, const int* __restrict__ ridx,
    int* __restrict__ out, unsigned int cap) {
  __shared__ unsigned int h[256];
  __shared__ uint64_t topk[TOPK];
  __shared__ unsigned int cnt2;
  __shared__ uint64_t sh_prefix;
  __shared__ unsigned int sh_k;
  const int tid = threadIdx.x;
  unsigned int n = counters[0];
  if (n > cap) n = cap;
  if (tid == 0) { sh_prefix = 0; sh_k = TOPK; cnt2 = 0; }

  for (int byte = 7; byte >= 0; --byte) {
    for (int b = tid; b < 256; b += 1024) h[b] = 0;
    __syncthreads();
    const uint64_t prefix = sh_prefix;
    const uint64_t mask = (byte == 7) ? 0ull : (~0ull << (8 * (byte + 1)));
    for (unsigned int i = tid; i < n; i += 1024) {
      uint64_t key = cand[i];
      if ((key & mask) == prefix)
        atomicAdd(&h[(unsigned int)(key >> (8 * byte)) & 255u], 1u);
    }
    __syncthreads();
    if (tid == 0) {
      unsigned int k = sh_k, cum = 0; int chosen = 0;
      for (int v = 255; v >= 0; --v) {
        if (cum + h[v] >= k) { chosen = v; sh_k = k - cum; break; }
        cum += h[v];
      }
      sh_prefix = prefix | (((uint64_t)chosen) << (8 * byte));
    }
    __syncthreads();
  }
  const uint64_t kstar = sh_prefix;

  for (int t = tid; t < TOPK; t += 1024) topk[t] = 0;
  __syncthreads();
  for (unsigned int i = tid; i < n; i += 1024) {
    uint64_t key = cand[i];
    if (key >= kstar) {
      unsigned int pos = atomicAdd(&cnt2, 1u);
      if (pos < TOPK) topk[pos] = key;
    }
  }
  __syncthreads();

  for (int k2 = 2; k2 <= TOPK; k2 <<= 1) {
    for (int j2 = k2 >> 1; j2 > 0; j2 >>= 1) {
      if (tid < TOPK) {
        int ixj = tid ^ j2;
        if (ixj > tid) {
          bool asc = ((tid & k2) == 0);
          uint64_t a = topk[tid], b = topk[ixj];
          if (asc ? (a < b) : (a > b)) { topk[tid] = b; topk[ixj] = a; }
        }
      }
      __syncthreads();
    }
  }

  if (tid < TOPK) {
    uint64_t key = topk[tid];
    unsigned int idx = ~((unsigned int)key);
    if (idx >= 104857600u) idx = 0;           // safety clamp (degenerate only)
    unsigned int s   = idx / 51200u;          // n_r*K*K = 2048*25
    unsigned int rem = idx % 51200u;
    unsigned int r   = rem / 25u;
    unsigned int sij = rem % 25u;
    out[0 * TOPK + tid] = (int)s;                       // first_node_src
    out[1 * TOPK + tid] = (int)r;                       // first_node_ref
    out[2 * TOPK + tid] = sidx[s * NK + sij / 5u];      // second_node_src
    out[3 * TOPK + tid] = ridx[r * NK + sij % 5u];      // second_node_ref
  }
}

extern "C" void kernel_launch(void* const* d_in, const int* in_sizes, int n_in,
                              void* d_out, int out_size, void* d_ws, size_t ws_size,
                              hipStream_t stream) {
  const float* src = (const float*)d_in[0];
  const float* ref = (const float*)d_in[1];
  const float* L   = (const float*)d_in[2];
  char* ws = (char*)d_ws;
  int*          sidx  = (int*)(ws + OFF_SIDX);
  float*        sdist = (float*)(ws + OFF_SDIST);
  int*          ridx  = (int*)(ws + OFF_RIDX);
  float*        rdist = (float*)(ws + OFF_RDIST);
  unsigned int* rmax  = (unsigned int*)(ws + OFF_RMAX);
  unsigned int* cnts  = (unsigned int*)(ws + OFF_CNT);
  uint64_t*     cand  = (uint64_t*)(ws + OFF_CAND);
  int*          out   = (int*)d_out;

  unsigned int cap = 0;
  if (ws_size > (size_t)OFF_CAND + 8) {
    size_t c = (ws_size - (size_t)OFF_CAND) / 8;
    cap = (c > CAP_MAX) ? CAP_MAX : (unsigned int)c;
  }

  knn_kernel<<<512, 256, 0, stream>>>(src, ref, sidx, sdist, ridx, rdist);
  rowmax_kernel<<<N_PTS, 256, 0, stream>>>(L, sidx, sdist, ridx, rdist, rmax);
  thresh_kernel<<<1, 1024, 0, stream>>>(rmax, cnts);
  collect_kernel<<<N_PTS, 256, 0, stream>>>(L, sidx, sdist, ridx, rdist, rmax, cnts, cand, cap);
  select_kernel<<<1, 1024, 0, stream>>>(cand, cnts, sidx, ridx, out, cap);
}

// Round 2
// 318.099 us; speedup vs baseline: 1.0228x; 1.0228x over previous
//
#include <hip/hip_runtime.h>
#include <stdint.h>

#define N_PTS 2048
#define NK 5
#define TOPK 512
#define CAP_MAX 262144u

// frozen arithmetic (r9-verified bit-exact vs np oracle):
//   d2 = fma(dz,dz, fma(dx,dx, dy*dy)); d = sqrt(max(d2,0))
//   q = fdiv(diff*diff, 0.01f); temp = max(1-q,0); v = (L*temp)*A
// tie rule: value desc, flat idx asc (key (vb<<32)|~idx descending)
// rejection bounds (exact under rounding, temp<=1, A<1):
//   v <= fmul_rn(Lsr,temp) <= Lsr
// div-free screen bound (rowmax phase A), RN-monotone proof:
//   ts = fma(dsq,-99,1):  99*d <= RN(d/0.01f) since d/0.01f = d*100.0000022
//   and RN(x)>=x*(1-2^-24)  =>  ts >= temp  =>  RN(Lsr*ts_max) >= every cell ub >= v

// ws layout (bytes):
//      0  src_ne_idx   int[10240]    (40960)
//  40960  src_ne_dist  f32[10240]    (40960)
//  81920  ref_ne_idx   int[10240]    (40960)
// 122880  ref_ne_dist  f32[10240]    (40960)
// 163840  rowmax       uint[2048]    (8192)
// 172032  counters     uint[8]       (32)   [0]=cand_count [3]=T
// 172064  cand         uint64[cap]
#define OFF_SIDX   0
#define OFF_SDIST  40960
#define OFF_RIDX   81920
#define OFF_RDIST  122880
#define OFF_RMAX   163840
#define OFF_CNT    172032
#define OFF_CAND   172064

__device__ __forceinline__ unsigned long long shflxor64(unsigned long long v, int mask) {
  unsigned lo = (unsigned)v, hi = (unsigned)(v >> 32);
  lo = (unsigned)__shfl_xor((int)lo, mask);
  hi = (unsigned)__shfl_xor((int)hi, mask);
  return ((unsigned long long)hi << 32) | lo;
}

// ---------------- KNN: 512 blocks, 8 points/block, 32 lanes/point ------------
__global__ __launch_bounds__(256) void knn_kernel(
    const float* __restrict__ src, const float* __restrict__ ref,
    int* __restrict__ sidx, float* __restrict__ sdist,
    int* __restrict__ ridx, float* __restrict__ rdist) {
  __shared__ float sx[N_PTS], sy[N_PTS], sz[N_PTS];
  const bool is_ref = blockIdx.x >= 256;
  const float* pts = is_ref ? ref : src;
  int*   oidx  = is_ref ? ridx : sidx;
  float* odist = is_ref ? rdist : sdist;
  const int blk = is_ref ? (blockIdx.x - 256) : blockIdx.x;

  for (int t = threadIdx.x; t < N_PTS; t += 256) {
    sx[t] = pts[3 * t + 0];
    sy[t] = pts[3 * t + 1];
    sz[t] = pts[3 * t + 2];
  }
  __syncthreads();

  const int p = blk * 8 + (threadIdx.x >> 5);
  const int u = threadIdx.x & 31;
  const float px = sx[p], py = sy[p], pz = sz[p];

  unsigned long long best[6];
#pragma unroll
  for (int k = 0; k < 6; ++k) best[k] = ~0ull;

  for (int j = u; j < N_PTS; j += 32) {
    float dx = __fsub_rn(px, sx[j]);
    float dy = __fsub_rn(py, sy[j]);
    float dz = __fsub_rn(pz, sz[j]);
    float d2 = __builtin_fmaf(dz, dz,
                 __builtin_fmaf(dx, dx, __fmul_rn(dy, dy)));
    float d = __fsqrt_rn(fmaxf(d2, 0.0f));
    unsigned long long key = (((unsigned long long)__float_as_uint(d)) << 32)
                           | (unsigned)j;
    if (key < best[5]) {
      best[5] = key;
#pragma unroll
      for (int k = 5; k >= 1; --k)
        if (best[k] < best[k - 1]) {
          unsigned long long t = best[k]; best[k] = best[k - 1]; best[k - 1] = t;
        }
    }
  }

  int h = 0;
  unsigned long long win[6];
#pragma unroll
  for (int round = 0; round < 6; ++round) {
    unsigned long long my = (h < 6) ? best[h] : ~0ull;
    unsigned long long m = my;
#pragma unroll
    for (int msk = 16; msk >= 1; msk >>= 1) {
      unsigned long long o = shflxor64(m, msk);
      if (o < m) m = o;
    }
    win[round] = m;
    if (my == m) ++h;
  }

  if (u == 0) {
#pragma unroll
    for (int m = 1; m <= NK; ++m) {     // drop win[0] == self (d = 0)
      oidx[p * NK + m - 1]  = (int)(win[m] & 0xFFFFFFFFull);
      odist[p * NK + m - 1] = __uint_as_float((unsigned)(win[m] >> 32));
    }
  }
}

// ---------------- pass 1: EXACT per-row max, screen-then-verify --------------
// Phase A: all-LDS div-free screen ubcol[r] >= every cell v of column r
//   (proof in header); per wave, exact column max of its top-2 screen-ub
//   columns computed with the 25 cells spread over 25 lanes (parallel
//   gathers, wave max-reduce) -> s_max near-final, zero serialization.
// Phase B: only columns with ubcol > s_max rescanned with the frozen exact
//   chain + old gating. Every cell with v > s_max has ubcol >= ub >= v >
//   s_max => covered => final s_max is the EXACT row max (s_max only ever
//   holds exactly-computed v). rowmax identical => T identical => output
//   identical; collect keeps its exact row-skip.
__global__ __launch_bounds__(256) void rowmax_kernel(
    const float* __restrict__ L,
    const int* __restrict__ sidx, const float* __restrict__ sdist,
    const int* __restrict__ ridx, const float* __restrict__ rdist,
    unsigned int* __restrict__ rowmax) {
  __shared__ float rdsh[N_PTS * NK];   // 40960 B: ALL ref neighbor dists
  __shared__ float ubcol[N_PTS];       //  8192 B: per-column screen bound
  __shared__ float sdsh[NK];
  __shared__ int   snsh[NK];
  __shared__ unsigned int s_max;
  const int s = blockIdx.x, tid = threadIdx.x;
  const float* __restrict__ Lg = L + (size_t)s * N_PTS;
  if (tid < NK) { snsh[tid] = sidx[s * NK + tid]; sdsh[tid] = sdist[s * NK + tid]; }
  if (tid == 0) s_max = 0;
  {
    const float4* g4 = (const float4*)rdist;   // OFF_RDIST is 16B-aligned
    float4* l4 = (float4*)rdsh;
    for (int c = tid; c < N_PTS * NK / 4; c += 256) l4[c] = g4[c];
  }
  __syncthreads();

  float sd[NK];
#pragma unroll
  for (int i = 0; i < NK; ++i) sd[i] = sdsh[i];
  volatile unsigned int* vmax = &s_max;
  const int lane = tid & 63;

  // ---- Phase A: screen all columns; keep per-thread top-2 by screen-ub ----
  unsigned long long b0 = 0ull, b1 = 0ull;     // (ubs_bits<<32)|r, ubs>=0
#pragma unroll
  for (int k = 0; k < N_PTS / 256; ++k) {
    const int r = tid + k * 256;
    const float Lsr = Lg[r];                   // coalesced stream
    float rd[NK];
#pragma unroll
    for (int j = 0; j < NK; ++j) rd[j] = rdsh[r * NK + j];   // stride-5: conflict-free
    float tsmax = 0.0f;
#pragma unroll
    for (int i = 0; i < NK; ++i)
#pragma unroll
      for (int j = 0; j < NK; ++j) {
        float diff = __fsub_rn(sd[i], rd[j]);
        float dsq  = __fmul_rn(diff, diff);
        float ts   = __builtin_fmaf(dsq, -99.0f, 1.0f);      // >= exact temp
        tsmax = fmaxf(tsmax, ts);
      }
    float ubs = (Lsr > 0.0f) ? __fmul_rn(Lsr, tsmax) : 0.0f; // >= every cell ub
    ubcol[r] = ubs;
    unsigned long long key = (((unsigned long long)__float_as_uint(ubs)) << 32)
                           | (unsigned)r;
    if (key > b0) { b1 = b0; b0 = key; } else if (key > b1) b1 = key;
  }

  // per-wave top-2 columns: exact column max, 25 cells across 25 lanes
  int h = 0;
  for (int round = 0; round < 2; ++round) {
    unsigned long long my = (h == 0) ? b0 : ((h == 1) ? b1 : 0ull);
    unsigned long long w = my;
#pragma unroll
    for (int msk = 32; msk >= 1; msk >>= 1) {
      unsigned long long o = shflxor64(w, msk);
      if (o > w) w = o;
    }
    if (my == w && w != 0ull) ++h;             // unique keys (r embedded)
    if ((unsigned)(w >> 32) == 0u) continue;   // no positive ub in wave's columns
    const int rwin = (int)(w & 0xFFFFFFFFull);
    unsigned int vb = 0;
    if (lane < NK * NK) {
      const int i = lane / NK, j = lane - i * NK;
      float diff = __fsub_rn(sdsh[i], rdsh[rwin * NK + j]);  // LDS broadcast
      float dsq  = __fmul_rn(diff, diff);
      if (dsq < 0.0101f) {
        float q    = __fdiv_rn(dsq, 0.01f);
        float temp = fmaxf(__fsub_rn(1.0f, q), 0.0f);
        if (temp > 0.0f) {
          float ub = __fmul_rn(Lg[rwin], temp);              // frozen inner term
          float a  = L[(size_t)snsh[i] * N_PTS + ridx[rwin * NK + j]];
          float v  = __fmul_rn(ub, a);                       // frozen chain
          if (v > 0.0f) vb = __float_as_uint(v);
        }
      }
    }
#pragma unroll
    for (int msk = 32; msk >= 1; msk >>= 1) {
      unsigned int o = (unsigned)__shfl_xor((int)vb, msk);
      if (o > vb) vb = o;
    }
    if (lane == 0 && vb > *vmax) atomicMax(&s_max, vb);
  }
  __syncthreads();

  // ---- Phase B: exact completion of survivors (ubcol > current max) ----
  for (int k = 0; k < N_PTS / 256; ++k) {
    const int r = tid + k * 256;
    if (!(ubcol[r] > __uint_as_float(*vmax))) continue;      // v <= ubcol <= smax
    const float Lsr = Lg[r];
    float rd[NK]; int rn[NK];
#pragma unroll
    for (int j = 0; j < NK; ++j) { rd[j] = rdsh[r * NK + j]; rn[j] = ridx[r * NK + j]; }
    unsigned int lmax = *vmax;
#pragma unroll
    for (int i = 0; i < NK; ++i) {
      const float* __restrict__ Arow = L + (size_t)snsh[i] * N_PTS;
#pragma unroll
      for (int j = 0; j < NK; ++j) {
        float diff = __fsub_rn(sd[i], rd[j]);
        float dsq  = __fmul_rn(diff, diff);
        if (dsq >= 0.0101f) continue;                        // temp provably 0
        float q    = __fdiv_rn(dsq, 0.01f);
        float temp = fmaxf(__fsub_rn(1.0f, q), 0.0f);
        if (temp <= 0.0f) continue;
        float ub   = __fmul_rn(Lsr, temp);                   // frozen inner term
        if (__float_as_uint(ub) <= lmax && ub <= __uint_as_float(*vmax)) continue;
        float v = __fmul_rn(ub, Arow[rn[j]]);                // frozen chain
        unsigned int vb2 = __float_as_uint(v);
        if (v > 0.0f && vb2 > lmax) lmax = vb2;
      }
    }
    if (lmax > *vmax) atomicMax(&s_max, lmax);
  }
  __syncthreads();
  if (tid == 0) rowmax[s] = s_max;
}

// ---------------- threshold: T = 512th-largest row max; zero counter ---------
// count(v >= T) >= 512 guaranteed: each of the top-512 rows contributes >= 1.
__global__ __launch_bounds__(1024) void thresh_kernel(
    const unsigned int* __restrict__ rowmax, unsigned int* __restrict__ counters) {
  __shared__ unsigned int a[N_PTS];
  const int tid = threadIdx.x;
  for (int t = tid; t < N_PTS; t += 1024) a[t] = rowmax[t];
  __syncthreads();
  for (int k2 = 2; k2 <= N_PTS; k2 <<= 1) {
    for (int j2 = k2 >> 1; j2 > 0; j2 >>= 1) {
      for (int e = 0; e < N_PTS / 1024; ++e) {
        int i = tid + e * 1024;
        int pj = i ^ j2;
        if (pj > i) {
          bool blk = ((i & k2) == 0);
          unsigned int x = a[i], y = a[pj];
          if (blk ? (x < y) : (x > y)) { a[i] = y; a[pj] = x; }
        }
      }
      __syncthreads();
    }
  }
  if (tid == 0) {
    counters[3] = a[TOPK - 1];
    counters[0] = 0;
  }
}

// ---------------- pass 2: collect, static Lsr < T rejection ------------------
__global__ __launch_bounds__(256) void collect_kernel(
    const float* __restrict__ L,
    const int* __restrict__ sidx, const float* __restrict__ sdist,
    const int* __restrict__ ridx, const float* __restrict__ rdist,
    const unsigned int* __restrict__ rowmax,
    unsigned int* __restrict__ counters, uint64_t* __restrict__ cand,
    unsigned int cap) {
  __shared__ float Lrow[N_PTS];
  __shared__ float sdsh[NK];
  __shared__ int   snsh[NK];
  const int s = blockIdx.x, tid = threadIdx.x;
  const unsigned int T = counters[3];
  if (rowmax[s] < T) return;            // uniform: whole row can't contribute
  const float T_f = __uint_as_float(T);
  if (tid < NK) { snsh[tid] = sidx[s * NK + tid]; sdsh[tid] = sdist[s * NK + tid]; }
  {
    const float4* src4 = (const float4*)(L + (size_t)s * N_PTS);
    float4* dst4 = (float4*)Lrow;
    for (int c = tid; c < N_PTS / 4; c += 256) dst4[c] = src4[c];
  }
  __syncthreads();

  float sd[NK];
#pragma unroll
  for (int i = 0; i < NK; ++i) sd[i] = sdsh[i];

  for (int r = tid; r < N_PTS; r += 256) {
    float Lsr = Lrow[r];
    if (Lsr < T_f) continue;                             // v <= Lsr < T
    float rd[NK]; int rn[NK];
#pragma unroll
    for (int j = 0; j < NK; ++j) { rd[j] = rdist[r * NK + j]; rn[j] = ridx[r * NK + j]; }
#pragma unroll
    for (int i = 0; i < NK; ++i) {
      const float* __restrict__ Arow = L + (size_t)snsh[i] * N_PTS;
#pragma unroll
      for (int j = 0; j < NK; ++j) {
        float diff = __fsub_rn(sd[i], rd[j]);
        float dsq  = __fmul_rn(diff, diff);
        if (dsq >= 0.0101f) continue;
        float q    = __fdiv_rn(dsq, 0.01f);
        float temp = fmaxf(__fsub_rn(1.0f, q), 0.0f);
        if (temp <= 0.0f) continue;
        float ub   = __fmul_rn(Lsr, temp);
        if (ub < T_f) continue;                          // v <= ub < T
        float v = __fmul_rn(ub, Arow[rn[j]]);            // frozen chain
        unsigned int vb = __float_as_uint(v);
        if (v > 0.0f && vb >= T) {
          unsigned int pos = atomicAdd(&counters[0], 1u);
          if (pos < cap) {
            unsigned int idx = ((unsigned int)s * (unsigned int)N_PTS
                                + (unsigned int)r) * 25u
                             + (unsigned int)i * 5u + (unsigned int)j;
            cand[pos] = (((uint64_t)vb) << 32) | (uint64_t)((uint32_t)(~idx));
          }
        }
      }
    }
  }
}

// ---------------- exact top-512: byte radix-select + bitonic sort ------------
__global__ __launch_bounds__(1024) void select_kernel(
    const uint64_t* __restrict__ cand, const unsigned int* __restrict__ counters,
    const int* __restrict__ sidx, const int* __restrict__ ridx,
    int* __restrict__ out, unsigned int cap) {
  __shared__ unsigned int h[256];
  __shared__ uint64_t topk[TOPK];
  __shared__ unsigned int cnt2;
  __shared__ uint64_t sh_prefix;
  __shared__ unsigned int sh_k;
  const int tid = threadIdx.x;
  unsigned int n = counters[0];
  if (n > cap) n = cap;
  if (tid == 0) { sh_prefix = 0; sh_k = TOPK; cnt2 = 0; }

  for (int byte = 7; byte >= 0; --byte) {
    for (int b = tid; b < 256; b += 1024) h[b] = 0;
    __syncthreads();
    const uint64_t prefix = sh_prefix;
    const uint64_t mask = (byte == 7) ? 0ull : (~0ull << (8 * (byte + 1)));
    for (unsigned int i = tid; i < n; i += 1024) {
      uint64_t key = cand[i];
      if ((key & mask) == prefix)
        atomicAdd(&h[(unsigned int)(key >> (8 * byte)) & 255u], 1u);
    }
    __syncthreads();
    if (tid == 0) {
      unsigned int k = sh_k, cum = 0; int chosen = 0;
      for (int v = 255; v >= 0; --v) {
        if (cum + h[v] >= k) { chosen = v; sh_k = k - cum; break; }
        cum += h[v];
      }
      sh_prefix = prefix | (((uint64_t)chosen) << (8 * byte));
    }
    __syncthreads();
  }
  const uint64_t kstar = sh_prefix;

  for (int t = tid; t < TOPK; t += 1024) topk[t] = 0;
  __syncthreads();
  for (unsigned int i = tid; i < n; i += 1024) {
    uint64_t key = cand[i];
    if (key >= kstar) {
      unsigned int pos = atomicAdd(&cnt2, 1u);
      if (pos < TOPK) topk[pos] = key;
    }
  }
  __syncthreads();

  for (int k2 = 2; k2 <= TOPK; k2 <<= 1) {
    for (int j2 = k2 >> 1; j2 > 0; j2 >>= 1) {
      if (tid < TOPK) {
        int ixj = tid ^ j2;
        if (ixj > tid) {
          bool asc = ((tid & k2) == 0);
          uint64_t a = topk[tid], b = topk[ixj];
          if (asc ? (a < b) : (a > b)) { topk[tid] = b; topk[ixj] = a; }
        }
      }
      __syncthreads();
    }
  }

  if (tid < TOPK) {
    uint64_t key = topk[tid];
    unsigned int idx = ~((unsigned int)key);
    if (idx >= 104857600u) idx = 0;           // safety clamp (degenerate only)
    unsigned int s   = idx / 51200u;          // n_r*K*K = 2048*25
    unsigned int rem = idx % 51200u;
    unsigned int r   = rem / 25u;
    unsigned int sij = rem % 25u;
    out[0 * TOPK + tid] = (int)s;                       // first_node_src
    out[1 * TOPK + tid] = (int)r;                       // first_node_ref
    out[2 * TOPK + tid] = sidx[s * NK + sij / 5u];      // second_node_src
    out[3 * TOPK + tid] = ridx[r * NK + sij % 5u];      // second_node_ref
  }
}

extern "C" void kernel_launch(void* const* d_in, const int* in_sizes, int n_in,
                              void* d_out, int out_size, void* d_ws, size_t ws_size,
                              hipStream_t stream) {
  const float* src = (const float*)d_in[0];
  const float* ref = (const float*)d_in[1];
  const float* L   = (const float*)d_in[2];
  char* ws = (char*)d_ws;
  int*          sidx  = (int*)(ws + OFF_SIDX);
  float*        sdist = (float*)(ws + OFF_SDIST);
  int*          ridx  = (int*)(ws + OFF_RIDX);
  float*        rdist = (float*)(ws + OFF_RDIST);
  unsigned int* rmax  = (unsigned int*)(ws + OFF_RMAX);
  unsigned int* cnts  = (unsigned int*)(ws + OFF_CNT);
  uint64_t*     cand  = (uint64_t*)(ws + OFF_CAND);
  int*          out   = (int*)d_out;

  unsigned int cap = 0;
  if (ws_size > (size_t)OFF_CAND + 8) {
    size_t c = (ws_size - (size_t)OFF_CAND) / 8;
    cap = (c > CAP_MAX) ? CAP_MAX : (unsigned int)c;
  }

  knn_kernel<<<512, 256, 0, stream>>>(src, ref, sidx, sdist, ridx, rdist);
  rowmax_kernel<<<N_PTS, 256, 0, stream>>>(L, sidx, sdist, ridx, rdist, rmax);
  thresh_kernel<<<1, 1024, 0, stream>>>(rmax, cnts);
  collect_kernel<<<N_PTS, 256, 0, stream>>>(L, sidx, sdist, ridx, rdist, rmax, cnts, cand, cap);
  select_kernel<<<1, 1024, 0, stream>>>(cand, cnts, sidx, ridx, out, cap);
}

// Round 3
// 252.192 us; speedup vs baseline: 1.2901x; 1.2613x over previous
//
#include <hip/hip_runtime.h>
#include <stdint.h>

#define N_PTS 2048
#define NK 5
#define TOPK 512
#define CAP_MAX 262144u

// frozen arithmetic (r9-verified bit-exact vs np oracle):
//   d2 = fma(dz,dz, fma(dx,dx, dy*dy)); d = sqrt(max(d2,0))
//   q = fdiv(diff*diff, 0.01f); temp = max(1-q,0); v = (L*temp)*A
// tie rule: value desc, flat idx asc (key (vb<<32)|~idx descending)
// rejection bounds (exact under rounding, temp<=1, A<1, L>=0, A>=0):
//   v <= fmul_rn(Lsr,temp) <= Lsr
// div-free cell pre-gate (exact, RN-monotone):
//   q = RN(dsq/0.01f) >= 99.9999*dsq  =>  1-q <= 1-99*dsq
//   temp = RN(1-q) <= RN(1-99*dsq) = fma(dsq,-99,1) = ts
//   => ubt = RN(Lsr*ts) >= RN(Lsr*temp) = ub >= v   (all operands >= 0)

// ws layout (bytes):
//      0  src_ne_idx   int[10240]    (40960)
//  40960  src_ne_dist  f32[10240]    (40960)
//  81920  ref_ne_idx   int[10240]    (40960)
// 122880  ref_ne_dist  f32[10240]    (40960)
// 163840  rowmax       uint[2048]    (8192)
// 172032  counters     uint[8]       (32)   [0]=cand_count [3]=T
// 172064  cand         uint64[cap]
#define OFF_SIDX   0
#define OFF_SDIST  40960
#define OFF_RIDX   81920
#define OFF_RDIST  122880
#define OFF_RMAX   163840
#define OFF_CNT    172032
#define OFF_CAND   172064

__device__ __forceinline__ unsigned long long shflxor64(unsigned long long v, int mask) {
  unsigned lo = (unsigned)v, hi = (unsigned)(v >> 32);
  lo = (unsigned)__shfl_xor((int)lo, mask);
  hi = (unsigned)__shfl_xor((int)hi, mask);
  return ((unsigned long long)hi << 32) | lo;
}

// ---------------- KNN: 512 blocks, 8 points/block, 32 lanes/point ------------
__global__ __launch_bounds__(256) void knn_kernel(
    const float* __restrict__ src, const float* __restrict__ ref,
    int* __restrict__ sidx, float* __restrict__ sdist,
    int* __restrict__ ridx, float* __restrict__ rdist) {
  __shared__ float sx[N_PTS], sy[N_PTS], sz[N_PTS];
  const bool is_ref = blockIdx.x >= 256;
  const float* pts = is_ref ? ref : src;
  int*   oidx  = is_ref ? ridx : sidx;
  float* odist = is_ref ? rdist : sdist;
  const int blk = is_ref ? (blockIdx.x - 256) : blockIdx.x;

  for (int t = threadIdx.x; t < N_PTS; t += 256) {
    sx[t] = pts[3 * t + 0];
    sy[t] = pts[3 * t + 1];
    sz[t] = pts[3 * t + 2];
  }
  __syncthreads();

  const int p = blk * 8 + (threadIdx.x >> 5);
  const int u = threadIdx.x & 31;
  const float px = sx[p], py = sy[p], pz = sz[p];

  unsigned long long best[6];
#pragma unroll
  for (int k = 0; k < 6; ++k) best[k] = ~0ull;

  for (int j = u; j < N_PTS; j += 32) {
    float dx = __fsub_rn(px, sx[j]);
    float dy = __fsub_rn(py, sy[j]);
    float dz = __fsub_rn(pz, sz[j]);
    float d2 = __builtin_fmaf(dz, dz,
                 __builtin_fmaf(dx, dx, __fmul_rn(dy, dy)));
    float d = __fsqrt_rn(fmaxf(d2, 0.0f));
    unsigned long long key = (((unsigned long long)__float_as_uint(d)) << 32)
                           | (unsigned)j;
    if (key < best[5]) {
      best[5] = key;
#pragma unroll
      for (int k = 5; k >= 1; --k)
        if (best[k] < best[k - 1]) {
          unsigned long long t = best[k]; best[k] = best[k - 1]; best[k - 1] = t;
        }
    }
  }

  int h = 0;
  unsigned long long win[6];
#pragma unroll
  for (int round = 0; round < 6; ++round) {
    unsigned long long my = (h < 6) ? best[h] : ~0ull;
    unsigned long long m = my;
#pragma unroll
    for (int msk = 16; msk >= 1; msk >>= 1) {
      unsigned long long o = shflxor64(m, msk);
      if (o < m) m = o;
    }
    win[round] = m;
    if (my == m) ++h;
  }

  if (u == 0) {
#pragma unroll
    for (int m = 1; m <= NK; ++m) {     // drop win[0] == self (d = 0)
      oidx[p * NK + m - 1]  = (int)(win[m] & 0xFFFFFFFFull);
      odist[p * NK + m - 1] = __uint_as_float((unsigned)(win[m] >> 32));
    }
  }
}

// ---------------- pass 1: exact per-row max (round-0 structure) --------------
// Round-0 structure kept intact (8.7KB LDS, no main-loop barriers, 256 thr).
// Two in-structure additions, both exactness-preserving:
//  (a) per-wave SEED: each wave exactly evaluates its slice's argmax-Lsr
//      column (25 cells over 25 lanes, frozen chain) and atomicMax's s_max
//      -> warm start, no barrier needed (gates are conservative under any
//      s_max visibility timing; s_max only ever holds exact cell values).
//  (b) div-free cell pre-gate ts/ubt (proof in header): fdiv + A-gather run
//      only for cells that can still beat lmax -> ~none after seed.
__global__ __launch_bounds__(256) void rowmax_kernel(
    const float* __restrict__ L,
    const int* __restrict__ sidx, const float* __restrict__ sdist,
    const int* __restrict__ ridx, const float* __restrict__ rdist,
    unsigned int* __restrict__ rowmax) {
  __shared__ float Lrow[N_PTS];
  __shared__ float sdsh[NK];
  __shared__ int   snsh[NK];
  __shared__ unsigned int s_max;
  const int s = blockIdx.x, tid = threadIdx.x;
  const int lane = tid & 63;
  if (tid < NK) { snsh[tid] = sidx[s * NK + tid]; sdsh[tid] = sdist[s * NK + tid]; }
  if (tid == 0) s_max = 0;
  {
    const float4* src4 = (const float4*)(L + (size_t)s * N_PTS);
    float4* dst4 = (float4*)Lrow;
    for (int c = tid; c < N_PTS / 4; c += 256) dst4[c] = src4[c];
  }
  __syncthreads();

  float sd[NK];
#pragma unroll
  for (int i = 0; i < NK; ++i) sd[i] = sdsh[i];
  volatile unsigned int* vmax = &s_max;

  // ---- (a) seed: per wave, exact max of its top-Lsr column ----
  {
    unsigned long long bk = 0ull;
#pragma unroll
    for (int k = 0; k < N_PTS / 256; ++k) {
      const int r = tid + k * 256;
      unsigned long long key =
          (((unsigned long long)__float_as_uint(Lrow[r])) << 32) | (unsigned)r;
      if (key > bk) bk = key;                 // Lrow >= 0: bit order == value order
    }
#pragma unroll
    for (int msk = 32; msk >= 1; msk >>= 1) {
      unsigned long long o = shflxor64(bk, msk);
      if (o > bk) bk = o;
    }
    const int rwin = (int)(bk & 0xFFFFFFFFull);
    const float Lsr = Lrow[rwin];
    unsigned int vb = 0;
    if (lane < NK * NK) {
      const int i = lane / NK, j = lane - i * NK;
      float diff = __fsub_rn(sdsh[i], rdist[rwin * NK + j]);  // frozen chain
      float dsq  = __fmul_rn(diff, diff);
      if (dsq < 0.0101f) {
        float q    = __fdiv_rn(dsq, 0.01f);
        float temp = fmaxf(__fsub_rn(1.0f, q), 0.0f);
        if (temp > 0.0f) {
          float ub = __fmul_rn(Lsr, temp);
          float a  = L[(size_t)snsh[i] * N_PTS + ridx[rwin * NK + j]];
          float v  = __fmul_rn(ub, a);
          if (v > 0.0f) vb = __float_as_uint(v);
        }
      }
    }
#pragma unroll
    for (int msk = 32; msk >= 1; msk >>= 1) {
      unsigned int o = (unsigned)__shfl_xor((int)vb, msk);
      if (o > vb) vb = o;
    }
    if (lane == 0 && vb > 0u) atomicMax(&s_max, vb);
  }

  // ---- main loop: round-0 shape + (b) div-free pre-gate, deferred ridx ----
  for (int r = tid; r < N_PTS; r += 256) {
    float Lsr = Lrow[r];
    if (Lsr <= __uint_as_float(*vmax)) continue;         // v <= Lsr <= smax
    float rd[NK];
#pragma unroll
    for (int j = 0; j < NK; ++j) rd[j] = rdist[r * NK + j];
    unsigned int lmax = *vmax;
#pragma unroll
    for (int i = 0; i < NK; ++i) {
#pragma unroll
      for (int j = 0; j < NK; ++j) {
        float diff = __fsub_rn(sd[i], rd[j]);
        float dsq  = __fmul_rn(diff, diff);
        if (dsq >= 0.0101f) continue;                    // temp provably 0
        float ts   = __builtin_fmaf(dsq, -99.0f, 1.0f);  // >= temp (exact)
        float ubt  = __fmul_rn(Lsr, ts);                 // >= ub >= v
        if (__float_as_uint(ubt) <= lmax) continue;      // div-free pre-gate
        float q    = __fdiv_rn(dsq, 0.01f);
        float temp = fmaxf(__fsub_rn(1.0f, q), 0.0f);
        if (temp <= 0.0f) continue;
        float ub   = __fmul_rn(Lsr, temp);               // frozen inner term
        if (__float_as_uint(ub) <= lmax) continue;
        float v = __fmul_rn(ub, L[(size_t)snsh[i] * N_PTS + ridx[r * NK + j]]);
        unsigned int vb = __float_as_uint(v);
        if (v > 0.0f && vb > lmax) lmax = vb;
      }
    }
    if (lmax > *vmax) atomicMax(&s_max, lmax);
  }
  __syncthreads();
  if (tid == 0) rowmax[s] = s_max;
}

// ---------------- threshold: T = 512th-largest row max; zero counter ---------
// count(v >= T) >= 512 guaranteed: each of the top-512 rows contributes >= 1.
__global__ __launch_bounds__(1024) void thresh_kernel(
    const unsigned int* __restrict__ rowmax, unsigned int* __restrict__ counters) {
  __shared__ unsigned int a[N_PTS];
  const int tid = threadIdx.x;
  for (int t = tid; t < N_PTS; t += 1024) a[t] = rowmax[t];
  __syncthreads();
  for (int k2 = 2; k2 <= N_PTS; k2 <<= 1) {
    for (int j2 = k2 >> 1; j2 > 0; j2 >>= 1) {
      for (int e = 0; e < N_PTS / 1024; ++e) {
        int i = tid + e * 1024;
        int pj = i ^ j2;
        if (pj > i) {
          bool blk = ((i & k2) == 0);
          unsigned int x = a[i], y = a[pj];
          if (blk ? (x < y) : (x > y)) { a[i] = y; a[pj] = x; }
        }
      }
      __syncthreads();
    }
  }
  if (tid == 0) {
    counters[3] = a[TOPK - 1];
    counters[0] = 0;
  }
}

// ---------------- pass 2: collect, static Lsr < T rejection ------------------
__global__ __launch_bounds__(256) void collect_kernel(
    const float* __restrict__ L,
    const int* __restrict__ sidx, const float* __restrict__ sdist,
    const int* __restrict__ ridx, const float* __restrict__ rdist,
    const unsigned int* __restrict__ rowmax,
    unsigned int* __restrict__ counters, uint64_t* __restrict__ cand,
    unsigned int cap) {
  __shared__ float Lrow[N_PTS];
  __shared__ float sdsh[NK];
  __shared__ int   snsh[NK];
  const int s = blockIdx.x, tid = threadIdx.x;
  const unsigned int T = counters[3];
  if (rowmax[s] < T) return;            // uniform: whole row can't contribute
  const float T_f = __uint_as_float(T);
  if (tid < NK) { snsh[tid] = sidx[s * NK + tid]; sdsh[tid] = sdist[s * NK + tid]; }
  {
    const float4* src4 = (const float4*)(L + (size_t)s * N_PTS);
    float4* dst4 = (float4*)Lrow;
    for (int c = tid; c < N_PTS / 4; c += 256) dst4[c] = src4[c];
  }
  __syncthreads();

  float sd[NK];
#pragma unroll
  for (int i = 0; i < NK; ++i) sd[i] = sdsh[i];

  for (int r = tid; r < N_PTS; r += 256) {
    float Lsr = Lrow[r];
    if (Lsr < T_f) continue;                             // v <= Lsr < T
    float rd[NK]; int rn[NK];
#pragma unroll
    for (int j = 0; j < NK; ++j) { rd[j] = rdist[r * NK + j]; rn[j] = ridx[r * NK + j]; }
#pragma unroll
    for (int i = 0; i < NK; ++i) {
      const float* __restrict__ Arow = L + (size_t)snsh[i] * N_PTS;
#pragma unroll
      for (int j = 0; j < NK; ++j) {
        float diff = __fsub_rn(sd[i], rd[j]);
        float dsq  = __fmul_rn(diff, diff);
        if (dsq >= 0.0101f) continue;
        float ts   = __builtin_fmaf(dsq, -99.0f, 1.0f);  // >= temp (exact)
        float ubt  = __fmul_rn(Lsr, ts);                 // >= ub >= v
        if (ubt < T_f) continue;                         // div-free pre-gate
        float q    = __fdiv_rn(dsq, 0.01f);
        float temp = fmaxf(__fsub_rn(1.0f, q), 0.0f);
        if (temp <= 0.0f) continue;
        float ub   = __fmul_rn(Lsr, temp);
        if (ub < T_f) continue;                          // v <= ub < T
        float v = __fmul_rn(ub, Arow[rn[j]]);            // frozen chain
        unsigned int vb = __float_as_uint(v);
        if (v > 0.0f && vb >= T) {
          unsigned int pos = atomicAdd(&counters[0], 1u);
          if (pos < cap) {
            unsigned int idx = ((unsigned int)s * (unsigned int)N_PTS
                                + (unsigned int)r) * 25u
                             + (unsigned int)i * 5u + (unsigned int)j;
            cand[pos] = (((uint64_t)vb) << 32) | (uint64_t)((uint32_t)(~idx));
          }
        }
      }
    }
  }
}

// ---------------- exact top-512: byte radix-select + bitonic sort ------------
__global__ __launch_bounds__(1024) void select_kernel(
    const uint64_t* __restrict__ cand, const unsigned int* __restrict__ counters,
    const int* __restrict__ sidx, const int* __restrict__ ridx,
    int* __restrict__ out, unsigned int cap) {
  __shared__ unsigned int h[256];
  __shared__ uint64_t topk[TOPK];
  __shared__ unsigned int cnt2;
  __shared__ uint64_t sh_prefix;
  __shared__ unsigned int sh_k;
  const int tid = threadIdx.x;
  unsigned int n = counters[0];
  if (n > cap) n = cap;
  if (tid == 0) { sh_prefix = 0; sh_k = TOPK; cnt2 = 0; }

  for (int byte = 7; byte >= 0; --byte) {
    for (int b = tid; b < 256; b += 1024) h[b] = 0;
    __syncthreads();
    const uint64_t prefix = sh_prefix;
    const uint64_t mask = (byte == 7) ? 0ull : (~0ull << (8 * (byte + 1)));
    for (unsigned int i = tid; i < n; i += 1024) {
      uint64_t key = cand[i];
      if ((key & mask) == prefix)
        atomicAdd(&h[(unsigned int)(key >> (8 * byte)) & 255u], 1u);
    }
    __syncthreads();
    if (tid == 0) {
      unsigned int k = sh_k, cum = 0; int chosen = 0;
      for (int v = 255; v >= 0; --v) {
        if (cum + h[v] >= k) { chosen = v; sh_k = k - cum; break; }
        cum += h[v];
      }
      sh_prefix = prefix | (((uint64_t)chosen) << (8 * byte));
    }
    __syncthreads();
  }
  const uint64_t kstar = sh_prefix;

  for (int t = tid; t < TOPK; t += 1024) topk[t] = 0;
  __syncthreads();
  for (unsigned int i = tid; i < n; i += 1024) {
    uint64_t key = cand[i];
    if (key >= kstar) {
      unsigned int pos = atomicAdd(&cnt2, 1u);
      if (pos < TOPK) topk[pos] = key;
    }
  }
  __syncthreads();

  for (int k2 = 2; k2 <= TOPK; k2 <<= 1) {
    for (int j2 = k2 >> 1; j2 > 0; j2 >>= 1) {
      if (tid < TOPK) {
        int ixj = tid ^ j2;
        if (ixj > tid) {
          bool asc = ((tid & k2) == 0);
          uint64_t a = topk[tid], b = topk[ixj];
          if (asc ? (a < b) : (a > b)) { topk[tid] = b; topk[ixj] = a; }
        }
      }
      __syncthreads();
    }
  }

  if (tid < TOPK) {
    uint64_t key = topk[tid];
    unsigned int idx = ~((unsigned int)key);
    if (idx >= 104857600u) idx = 0;           // safety clamp (degenerate only)
    unsigned int s   = idx / 51200u;          // n_r*K*K = 2048*25
    unsigned int rem = idx % 51200u;
    unsigned int r   = rem / 25u;
    unsigned int sij = rem % 25u;
    out[0 * TOPK + tid] = (int)s;                       // first_node_src
    out[1 * TOPK + tid] = (int)r;                       // first_node_ref
    out[2 * TOPK + tid] = sidx[s * NK + sij / 5u];      // second_node_src
    out[3 * TOPK + tid] = ridx[r * NK + sij % 5u];      // second_node_ref
  }
}

extern "C" void kernel_launch(void* const* d_in, const int* in_sizes, int n_in,
                              void* d_out, int out_size, void* d_ws, size_t ws_size,
                              hipStream_t stream) {
  const float* src = (const float*)d_in[0];
  const float* ref = (const float*)d_in[1];
  const float* L   = (const float*)d_in[2];
  char* ws = (char*)d_ws;
  int*          sidx  = (int*)(ws + OFF_SIDX);
  float*        sdist = (float*)(ws + OFF_SDIST);
  int*          ridx  = (int*)(ws + OFF_RIDX);
  float*        rdist = (float*)(ws + OFF_RDIST);
  unsigned int* rmax  = (unsigned int*)(ws + OFF_RMAX);
  unsigned int* cnts  = (unsigned int*)(ws + OFF_CNT);
  uint64_t*     cand  = (uint64_t*)(ws + OFF_CAND);
  int*          out   = (int*)d_out;

  unsigned int cap = 0;
  if (ws_size > (size_t)OFF_CAND + 8) {
    size_t c = (ws_size - (size_t)OFF_CAND) / 8;
    cap = (c > CAP_MAX) ? CAP_MAX : (unsigned int)c;
  }

  knn_kernel<<<512, 256, 0, stream>>>(src, ref, sidx, sdist, ridx, rdist);
  rowmax_kernel<<<N_PTS, 256, 0, stream>>>(L, sidx, sdist, ridx, rdist, rmax);
  thresh_kernel<<<1, 1024, 0, stream>>>(rmax, cnts);
  collect_kernel<<<N_PTS, 256, 0, stream>>>(L, sidx, sdist, ridx, rdist, rmax, cnts, cand, cap);
  select_kernel<<<1, 1024, 0, stream>>>(cand, cnts, sidx, ridx, out, cap);
}

// Round 4
// 235.817 us; speedup vs baseline: 1.3797x; 1.0694x over previous
//
#include <hip/hip_runtime.h>
#include <stdint.h>

#define N_PTS 2048
#define NK 5
#define TOPK 512
#define CAP_MAX 262144u

// frozen arithmetic (r9-verified bit-exact vs np oracle):
//   d2 = fma(dz,dz, fma(dx,dx, dy*dy)); d = sqrt(max(d2,0))
//   q = fdiv(diff*diff, 0.01f); temp = max(1-q,0); v = (L*temp)*A
// tie rule: value desc, flat idx asc (key (vb<<32)|~idx descending)
// rejection bounds (exact under rounding, temp<=1, A<1, L>=0, A>=0):
//   v <= fmul_rn(Lsr,temp) <= Lsr
// div-free cell pre-gate (exact, RN-monotone):
//   q = RN(dsq/0.01f) >= 99.9999*dsq  =>  1-q <= 1-99*dsq
//   temp = RN(1-q) <= RN(1-99*dsq) = fma(dsq,-99,1) = ts
//   => ubt = RN(Lsr*ts) >= RN(Lsr*temp) = ub >= v   (all operands >= 0)
// latency rule (r4): never place a gather-dependent value in the gate of the
//   next gather — gate on snapshot lmax, combine v's with fmaxf afterwards.

// ws layout (bytes):
//      0  src_ne_idx   int[10240]    (40960)
//  40960  src_ne_dist  f32[10240]    (40960)
//  81920  ref_ne_idx   int[10240]    (40960)
// 122880  ref_ne_dist  f32[10240]    (40960)
// 163840  rowmax       uint[2048]    (8192)
// 172032  counters     uint[8]       (32)   [0]=cand_count [3]=T
// 172064  cand         uint64[cap]
#define OFF_SIDX   0
#define OFF_SDIST  40960
#define OFF_RIDX   81920
#define OFF_RDIST  122880
#define OFF_RMAX   163840
#define OFF_CNT    172032
#define OFF_CAND   172064

__device__ __forceinline__ unsigned long long shflxor64(unsigned long long v, int mask) {
  unsigned lo = (unsigned)v, hi = (unsigned)(v >> 32);
  lo = (unsigned)__shfl_xor((int)lo, mask);
  hi = (unsigned)__shfl_xor((int)hi, mask);
  return ((unsigned long long)hi << 32) | lo;
}

// ---------------- KNN: 512 blocks, 8 points/block, 32 lanes/point ------------
__global__ __launch_bounds__(256) void knn_kernel(
    const float* __restrict__ src, const float* __restrict__ ref,
    int* __restrict__ sidx, float* __restrict__ sdist,
    int* __restrict__ ridx, float* __restrict__ rdist) {
  __shared__ float sx[N_PTS], sy[N_PTS], sz[N_PTS];
  const bool is_ref = blockIdx.x >= 256;
  const float* pts = is_ref ? ref : src;
  int*   oidx  = is_ref ? ridx : sidx;
  float* odist = is_ref ? rdist : sdist;
  const int blk = is_ref ? (blockIdx.x - 256) : blockIdx.x;

  for (int t = threadIdx.x; t < N_PTS; t += 256) {
    sx[t] = pts[3 * t + 0];
    sy[t] = pts[3 * t + 1];
    sz[t] = pts[3 * t + 2];
  }
  __syncthreads();

  const int p = blk * 8 + (threadIdx.x >> 5);
  const int u = threadIdx.x & 31;
  const float px = sx[p], py = sy[p], pz = sz[p];

  unsigned long long best[6];
#pragma unroll
  for (int k = 0; k < 6; ++k) best[k] = ~0ull;

  for (int j = u; j < N_PTS; j += 32) {
    float dx = __fsub_rn(px, sx[j]);
    float dy = __fsub_rn(py, sy[j]);
    float dz = __fsub_rn(pz, sz[j]);
    float d2 = __builtin_fmaf(dz, dz,
                 __builtin_fmaf(dx, dx, __fmul_rn(dy, dy)));
    float d = __fsqrt_rn(fmaxf(d2, 0.0f));
    unsigned long long key = (((unsigned long long)__float_as_uint(d)) << 32)
                           | (unsigned)j;
    if (key < best[5]) {
      best[5] = key;
#pragma unroll
      for (int k = 5; k >= 1; --k)
        if (best[k] < best[k - 1]) {
          unsigned long long t = best[k]; best[k] = best[k - 1]; best[k - 1] = t;
        }
    }
  }

  int h = 0;
  unsigned long long win[6];
#pragma unroll
  for (int round = 0; round < 6; ++round) {
    unsigned long long my = (h < 6) ? best[h] : ~0ull;
    unsigned long long m = my;
#pragma unroll
    for (int msk = 16; msk >= 1; msk >>= 1) {
      unsigned long long o = shflxor64(m, msk);
      if (o < m) m = o;
    }
    win[round] = m;
    if (my == m) ++h;
  }

  if (u == 0) {
#pragma unroll
    for (int m = 1; m <= NK; ++m) {     // drop win[0] == self (d = 0)
      oidx[p * NK + m - 1]  = (int)(win[m] & 0xFFFFFFFFull);
      odist[p * NK + m - 1] = __uint_as_float((unsigned)(win[m] >> 32));
    }
  }
}

// ---------------- pass 1: exact per-row max (round-0 structure) --------------
// r3 additions kept: (a) per-wave exact seed, (b) div-free cell pre-gate.
// r4 addition: CHAIN-BROKEN column evaluation. All 25 cells of a surviving
// column are gated on a register SNAPSHOT lmax (refreshed from s_max once per
// k-iteration); no lmax update between cells, so all passing cells' A-gathers
// are independent loads (pipelined, not serialized by the old
// gather->lmax->gate->gather chain). Column max combined with fmaxf (max of
// exactly-computed frozen-chain v's), one atomicMax per improving column.
// Stale gates are conservative => s_max still only ever holds exact v's =>
// rowmax exact => T identical => output identical.
__global__ __launch_bounds__(256) void rowmax_kernel(
    const float* __restrict__ L,
    const int* __restrict__ sidx, const float* __restrict__ sdist,
    const int* __restrict__ ridx, const float* __restrict__ rdist,
    unsigned int* __restrict__ rowmax) {
  __shared__ float Lrow[N_PTS];
  __shared__ float sdsh[NK];
  __shared__ int   snsh[NK];
  __shared__ unsigned int s_max;
  const int s = blockIdx.x, tid = threadIdx.x;
  const int lane = tid & 63;
  if (tid < NK) { snsh[tid] = sidx[s * NK + tid]; sdsh[tid] = sdist[s * NK + tid]; }
  if (tid == 0) s_max = 0;
  {
    const float4* src4 = (const float4*)(L + (size_t)s * N_PTS);
    float4* dst4 = (float4*)Lrow;
    for (int c = tid; c < N_PTS / 4; c += 256) dst4[c] = src4[c];
  }
  __syncthreads();

  float sd[NK];
#pragma unroll
  for (int i = 0; i < NK; ++i) sd[i] = sdsh[i];
  const float* __restrict__ Arow[NK];
#pragma unroll
  for (int i = 0; i < NK; ++i) Arow[i] = L + (size_t)snsh[i] * N_PTS;
  volatile unsigned int* vmax = &s_max;

  // ---- (a) seed: per wave, exact max of its top-Lsr column ----
  {
    unsigned long long bk = 0ull;
#pragma unroll
    for (int k = 0; k < N_PTS / 256; ++k) {
      const int r = tid + k * 256;
      unsigned long long key =
          (((unsigned long long)__float_as_uint(Lrow[r])) << 32) | (unsigned)r;
      if (key > bk) bk = key;                 // Lrow >= 0: bit order == value order
    }
#pragma unroll
    for (int msk = 32; msk >= 1; msk >>= 1) {
      unsigned long long o = shflxor64(bk, msk);
      if (o > bk) bk = o;
    }
    const int rwin = (int)(bk & 0xFFFFFFFFull);
    const float Lsr = Lrow[rwin];
    unsigned int vb = 0;
    if (lane < NK * NK) {
      const int i = lane / NK, j = lane - i * NK;
      float diff = __fsub_rn(sdsh[i], rdist[rwin * NK + j]);  // frozen chain
      float dsq  = __fmul_rn(diff, diff);
      if (dsq < 0.0101f) {
        float q    = __fdiv_rn(dsq, 0.01f);
        float temp = fmaxf(__fsub_rn(1.0f, q), 0.0f);
        if (temp > 0.0f) {
          float ub = __fmul_rn(Lsr, temp);
          float a  = L[(size_t)snsh[i] * N_PTS + ridx[rwin * NK + j]];
          float v  = __fmul_rn(ub, a);
          if (v > 0.0f) vb = __float_as_uint(v);
        }
      }
    }
#pragma unroll
    for (int msk = 32; msk >= 1; msk >>= 1) {
      unsigned int o = (unsigned)__shfl_xor((int)vb, msk);
      if (o > vb) vb = o;
    }
    if (lane == 0 && vb > 0u) atomicMax(&s_max, vb);
  }

  // ---- main loop: chain-broken snapshot-gated column evaluation ----
  unsigned int lmax = *vmax;                   // one volatile read post-seed
#pragma unroll 1
  for (int k = 0; k < N_PTS / 256; ++k) {
    const int r = tid + k * 256;
    { unsigned int sm = *vmax; if (sm > lmax) lmax = sm; }   // per-iter refresh
    const float Lsr = Lrow[r];
    const float lmaxf = __uint_as_float(lmax);
    if (Lsr <= lmaxf) continue;                // v <= Lsr <= smax
    float rd[NK]; int rn[NK];
#pragma unroll
    for (int j = 0; j < NK; ++j) { rd[j] = rdist[r * NK + j]; rn[j] = ridx[r * NK + j]; }
    float vcol = 0.0f;                         // column max of exact v's
#pragma unroll
    for (int i = 0; i < NK; ++i) {
#pragma unroll
      for (int j = 0; j < NK; ++j) {
        float diff = __fsub_rn(sd[i], rd[j]);
        float dsq  = __fmul_rn(diff, diff);
        if (dsq >= 0.0101f) continue;                    // temp provably 0
        float ts   = __builtin_fmaf(dsq, -99.0f, 1.0f);  // >= temp (exact)
        if (__fmul_rn(Lsr, ts) <= lmaxf) continue;       // div-free pre-gate
        float q    = __fdiv_rn(dsq, 0.01f);
        float temp = fmaxf(__fsub_rn(1.0f, q), 0.0f);
        if (temp <= 0.0f) continue;
        float ub   = __fmul_rn(Lsr, temp);               // frozen inner term
        if (ub <= lmaxf) continue;
        float v = __fmul_rn(ub, Arow[i][rn[j]]);         // frozen chain; gather
        vcol = fmaxf(vcol, v);                           // no lmax in the chain
      }
    }
    if (vcol > __uint_as_float(lmax)) {
      lmax = __float_as_uint(vcol);
      atomicMax(&s_max, lmax);
    }
  }
  __syncthreads();
  if (tid == 0) rowmax[s] = s_max;
}

// ---------------- threshold: T = 512th-largest row max; zero counter ---------
// count(v >= T) >= 512 guaranteed: each of the top-512 rows contributes >= 1.
__global__ __launch_bounds__(1024) void thresh_kernel(
    const unsigned int* __restrict__ rowmax, unsigned int* __restrict__ counters) {
  __shared__ unsigned int a[N_PTS];
  const int tid = threadIdx.x;
  for (int t = tid; t < N_PTS; t += 1024) a[t] = rowmax[t];
  __syncthreads();
  for (int k2 = 2; k2 <= N_PTS; k2 <<= 1) {
    for (int j2 = k2 >> 1; j2 > 0; j2 >>= 1) {
      for (int e = 0; e < N_PTS / 1024; ++e) {
        int i = tid + e * 1024;
        int pj = i ^ j2;
        if (pj > i) {
          bool blk = ((i & k2) == 0);
          unsigned int x = a[i], y = a[pj];
          if (blk ? (x < y) : (x > y)) { a[i] = y; a[pj] = x; }
        }
      }
      __syncthreads();
    }
  }
  if (tid == 0) {
    counters[3] = a[TOPK - 1];
    counters[0] = 0;
  }
}

// ---------------- pass 2: collect, static Lsr < T rejection ------------------
__global__ __launch_bounds__(256) void collect_kernel(
    const float* __restrict__ L,
    const int* __restrict__ sidx, const float* __restrict__ sdist,
    const int* __restrict__ ridx, const float* __restrict__ rdist,
    const unsigned int* __restrict__ rowmax,
    unsigned int* __restrict__ counters, uint64_t* __restrict__ cand,
    unsigned int cap) {
  __shared__ float Lrow[N_PTS];
  __shared__ float sdsh[NK];
  __shared__ int   snsh[NK];
  const int s = blockIdx.x, tid = threadIdx.x;
  const unsigned int T = counters[3];
  if (rowmax[s] < T) return;            // uniform: whole row can't contribute
  const float T_f = __uint_as_float(T);
  if (tid < NK) { snsh[tid] = sidx[s * NK + tid]; sdsh[tid] = sdist[s * NK + tid]; }
  {
    const float4* src4 = (const float4*)(L + (size_t)s * N_PTS);
    float4* dst4 = (float4*)Lrow;
    for (int c = tid; c < N_PTS / 4; c += 256) dst4[c] = src4[c];
  }
  __syncthreads();

  float sd[NK];
#pragma unroll
  for (int i = 0; i < NK; ++i) sd[i] = sdsh[i];

  for (int r = tid; r < N_PTS; r += 256) {
    float Lsr = Lrow[r];
    if (Lsr < T_f) continue;                             // v <= Lsr < T
    float rd[NK]; int rn[NK];
#pragma unroll
    for (int j = 0; j < NK; ++j) { rd[j] = rdist[r * NK + j]; rn[j] = ridx[r * NK + j]; }
#pragma unroll
    for (int i = 0; i < NK; ++i) {
      const float* __restrict__ Arow = L + (size_t)snsh[i] * N_PTS;
#pragma unroll
      for (int j = 0; j < NK; ++j) {
        float diff = __fsub_rn(sd[i], rd[j]);
        float dsq  = __fmul_rn(diff, diff);
        if (dsq >= 0.0101f) continue;
        float ts   = __builtin_fmaf(dsq, -99.0f, 1.0f);  // >= temp (exact)
        float ubt  = __fmul_rn(Lsr, ts);                 // >= ub >= v
        if (ubt < T_f) continue;                         // div-free pre-gate
        float q    = __fdiv_rn(dsq, 0.01f);
        float temp = fmaxf(__fsub_rn(1.0f, q), 0.0f);
        if (temp <= 0.0f) continue;
        float ub   = __fmul_rn(Lsr, temp);
        if (ub < T_f) continue;                          // v <= ub < T
        float v = __fmul_rn(ub, Arow[rn[j]]);            // frozen chain
        unsigned int vb = __float_as_uint(v);
        if (v > 0.0f && vb >= T) {
          unsigned int pos = atomicAdd(&counters[0], 1u);
          if (pos < cap) {
            unsigned int idx = ((unsigned int)s * (unsigned int)N_PTS
                                + (unsigned int)r) * 25u
                             + (unsigned int)i * 5u + (unsigned int)j;
            cand[pos] = (((uint64_t)vb) << 32) | (uint64_t)((uint32_t)(~idx));
          }
        }
      }
    }
  }
}

// ---------------- exact top-512: byte radix-select + bitonic sort ------------
__global__ __launch_bounds__(1024) void select_kernel(
    const uint64_t* __restrict__ cand, const unsigned int* __restrict__ counters,
    const int* __restrict__ sidx, const int* __restrict__ ridx,
    int* __restrict__ out, unsigned int cap) {
  __shared__ unsigned int h[256];
  __shared__ uint64_t topk[TOPK];
  __shared__ unsigned int cnt2;
  __shared__ uint64_t sh_prefix;
  __shared__ unsigned int sh_k;
  const int tid = threadIdx.x;
  unsigned int n = counters[0];
  if (n > cap) n = cap;
  if (tid == 0) { sh_prefix = 0; sh_k = TOPK; cnt2 = 0; }

  for (int byte = 7; byte >= 0; --byte) {
    for (int b = tid; b < 256; b += 1024) h[b] = 0;
    __syncthreads();
    const uint64_t prefix = sh_prefix;
    const uint64_t mask = (byte == 7) ? 0ull : (~0ull << (8 * (byte + 1)));
    for (unsigned int i = tid; i < n; i += 1024) {
      uint64_t key = cand[i];
      if ((key & mask) == prefix)
        atomicAdd(&h[(unsigned int)(key >> (8 * byte)) & 255u], 1u);
    }
    __syncthreads();
    if (tid == 0) {
      unsigned int k = sh_k, cum = 0; int chosen = 0;
      for (int v = 255; v >= 0; --v) {
        if (cum + h[v] >= k) { chosen = v; sh_k = k - cum; break; }
        cum += h[v];
      }
      sh_prefix = prefix | (((uint64_t)chosen) << (8 * byte));
    }
    __syncthreads();
  }
  const uint64_t kstar = sh_prefix;

  for (int t = tid; t < TOPK; t += 1024) topk[t] = 0;
  __syncthreads();
  for (unsigned int i = tid; i < n; i += 1024) {
    uint64_t key = cand[i];
    if (key >= kstar) {
      unsigned int pos = atomicAdd(&cnt2, 1u);
      if (pos < TOPK) topk[pos] = key;
    }
  }
  __syncthreads();

  for (int k2 = 2; k2 <= TOPK; k2 <<= 1) {
    for (int j2 = k2 >> 1; j2 > 0; j2 >>= 1) {
      if (tid < TOPK) {
        int ixj = tid ^ j2;
        if (ixj > tid) {
          bool asc = ((tid & k2) == 0);
          uint64_t a = topk[tid], b = topk[ixj];
          if (asc ? (a < b) : (a > b)) { topk[tid] = b; topk[ixj] = a; }
        }
      }
      __syncthreads();
    }
  }

  if (tid < TOPK) {
    uint64_t key = topk[tid];
    unsigned int idx = ~((unsigned int)key);
    if (idx >= 104857600u) idx = 0;           // safety clamp (degenerate only)
    unsigned int s   = idx / 51200u;          // n_r*K*K = 2048*25
    unsigned int rem = idx % 51200u;
    unsigned int r   = rem / 25u;
    unsigned int sij = rem % 25u;
    out[0 * TOPK + tid] = (int)s;                       // first_node_src
    out[1 * TOPK + tid] = (int)r;                       // first_node_ref
    out[2 * TOPK + tid] = sidx[s * NK + sij / 5u];      // second_node_src
    out[3 * TOPK + tid] = ridx[r * NK + sij % 5u];      // second_node_ref
  }
}

extern "C" void kernel_launch(void* const* d_in, const int* in_sizes, int n_in,
                              void* d_out, int out_size, void* d_ws, size_t ws_size,
                              hipStream_t stream) {
  const float* src = (const float*)d_in[0];
  const float* ref = (const float*)d_in[1];
  const float* L   = (const float*)d_in[2];
  char* ws = (char*)d_ws;
  int*          sidx  = (int*)(ws + OFF_SIDX);
  float*        sdist = (float*)(ws + OFF_SDIST);
  int*          ridx  = (int*)(ws + OFF_RIDX);
  float*        rdist = (float*)(ws + OFF_RDIST);
  unsigned int* rmax  = (unsigned int*)(ws + OFF_RMAX);
  unsigned int* cnts  = (unsigned int*)(ws + OFF_CNT);
  uint64_t*     cand  = (uint64_t*)(ws + OFF_CAND);
  int*          out   = (int*)d_out;

  unsigned int cap = 0;
  if (ws_size > (size_t)OFF_CAND + 8) {
    size_t c = (ws_size - (size_t)OFF_CAND) / 8;
    cap = (c > CAP_MAX) ? CAP_MAX : (unsigned int)c;
  }

  knn_kernel<<<512, 256, 0, stream>>>(src, ref, sidx, sdist, ridx, rdist);
  rowmax_kernel<<<N_PTS, 256, 0, stream>>>(L, sidx, sdist, ridx, rdist, rmax);
  thresh_kernel<<<1, 1024, 0, stream>>>(rmax, cnts);
  collect_kernel<<<N_PTS, 256, 0, stream>>>(L, sidx, sdist, ridx, rdist, rmax, cnts, cand, cap);
  select_kernel<<<1, 1024, 0, stream>>>(cand, cnts, sidx, ridx, out, cap);
}

// Round 5
// 200.530 us; speedup vs baseline: 1.6225x; 1.1760x over previous
//
#include <hip/hip_runtime.h>
#include <stdint.h>

#define N_PTS 2048
#define NK 5
#define TOPK 512
#define CAP_MAX 262144u

// frozen arithmetic (r9-verified bit-exact vs np oracle):
//   d2 = fma(dz,dz, fma(dx,dx, dy*dy)); d = sqrt(max(d2,0))
//   q = fdiv(diff*diff, 0.01f); temp = max(1-q,0); v = (L*temp)*A
// tie rule: value desc, flat idx asc (key (vb<<32)|~idx descending)
// rejection bounds (exact under rounding, temp<=1, A<1, L>=0, A>=0):
//   v <= fmul_rn(Lsr,temp) <= Lsr
// div-free cell pre-gate (exact, RN-monotone):
//   q = RN(dsq/0.01f) >= 99.9999*dsq  =>  1-q <= 1-99*dsq
//   temp = RN(1-q) <= RN(1-99*dsq) = fma(dsq,-99,1) = ts
//   => ubt = RN(Lsr*ts) >= RN(Lsr*temp) = ub >= v   (all operands >= 0)
// latency rule (r4): never place a gather-dependent value in the gate of the
//   next gather — gate on snapshot lmax, combine v's with fmaxf afterwards.
// serialization rule (r5): no serial per-bin scans on one lane (LDS latency
//   chains); no clustered-key LDS atomic histograms without wave-split.

// ws layout (bytes):
//      0  src_ne_idx   int[10240]    (40960)
//  40960  src_ne_dist  f32[10240]    (40960)
//  81920  ref_ne_idx   int[10240]    (40960)
// 122880  ref_ne_dist  f32[10240]    (40960)
// 163840  rowmax       uint[2048]    (8192)
// 172032  counters     uint[8]       (32)   [0]=cand_count [3]=T
// 172064  cand         uint64[cap]
#define OFF_SIDX   0
#define OFF_SDIST  40960
#define OFF_RIDX   81920
#define OFF_RDIST  122880
#define OFF_RMAX   163840
#define OFF_CNT    172032
#define OFF_CAND   172064

__device__ __forceinline__ unsigned long long shflxor64(unsigned long long v, int mask) {
  unsigned lo = (unsigned)v, hi = (unsigned)(v >> 32);
  lo = (unsigned)__shfl_xor((int)lo, mask);
  hi = (unsigned)__shfl_xor((int)hi, mask);
  return ((unsigned long long)hi << 32) | lo;
}

// ---------------- KNN: 512 blocks, 8 points/block, 32 lanes/point ------------
__global__ __launch_bounds__(256) void knn_kernel(
    const float* __restrict__ src, const float* __restrict__ ref,
    int* __restrict__ sidx, float* __restrict__ sdist,
    int* __restrict__ ridx, float* __restrict__ rdist) {
  __shared__ float sx[N_PTS], sy[N_PTS], sz[N_PTS];
  const bool is_ref = blockIdx.x >= 256;
  const float* pts = is_ref ? ref : src;
  int*   oidx  = is_ref ? ridx : sidx;
  float* odist = is_ref ? rdist : sdist;
  const int blk = is_ref ? (blockIdx.x - 256) : blockIdx.x;

  for (int t = threadIdx.x; t < N_PTS; t += 256) {
    sx[t] = pts[3 * t + 0];
    sy[t] = pts[3 * t + 1];
    sz[t] = pts[3 * t + 2];
  }
  __syncthreads();

  const int p = blk * 8 + (threadIdx.x >> 5);
  const int u = threadIdx.x & 31;
  const float px = sx[p], py = sy[p], pz = sz[p];

  unsigned long long best[6];
#pragma unroll
  for (int k = 0; k < 6; ++k) best[k] = ~0ull;

  for (int j = u; j < N_PTS; j += 32) {
    float dx = __fsub_rn(px, sx[j]);
    float dy = __fsub_rn(py, sy[j]);
    float dz = __fsub_rn(pz, sz[j]);
    float d2 = __builtin_fmaf(dz, dz,
                 __builtin_fmaf(dx, dx, __fmul_rn(dy, dy)));
    float d = __fsqrt_rn(fmaxf(d2, 0.0f));
    unsigned long long key = (((unsigned long long)__float_as_uint(d)) << 32)
                           | (unsigned)j;
    if (key < best[5]) {
      best[5] = key;
#pragma unroll
      for (int k = 5; k >= 1; --k)
        if (best[k] < best[k - 1]) {
          unsigned long long t = best[k]; best[k] = best[k - 1]; best[k - 1] = t;
        }
    }
  }

  int h = 0;
  unsigned long long win[6];
#pragma unroll
  for (int round = 0; round < 6; ++round) {
    unsigned long long my = (h < 6) ? best[h] : ~0ull;
    unsigned long long m = my;
#pragma unroll
    for (int msk = 16; msk >= 1; msk >>= 1) {
      unsigned long long o = shflxor64(m, msk);
      if (o < m) m = o;
    }
    win[round] = m;
    if (my == m) ++h;
  }

  if (u == 0) {
#pragma unroll
    for (int m = 1; m <= NK; ++m) {     // drop win[0] == self (d = 0)
      oidx[p * NK + m - 1]  = (int)(win[m] & 0xFFFFFFFFull);
      odist[p * NK + m - 1] = __uint_as_float((unsigned)(win[m] >> 32));
    }
  }
}

// ---------------- pass 1: exact per-row max (round-0 structure) --------------
// r3: (a) per-wave exact seed, (b) div-free cell pre-gate.
// r4: chain-broken snapshot-gated column evaluation (independent gathers,
//     fmaxf combine, one atomicMax per improving column). Exact.
__global__ __launch_bounds__(256) void rowmax_kernel(
    const float* __restrict__ L,
    const int* __restrict__ sidx, const float* __restrict__ sdist,
    const int* __restrict__ ridx, const float* __restrict__ rdist,
    unsigned int* __restrict__ rowmax) {
  __shared__ float Lrow[N_PTS];
  __shared__ float sdsh[NK];
  __shared__ int   snsh[NK];
  __shared__ unsigned int s_max;
  const int s = blockIdx.x, tid = threadIdx.x;
  const int lane = tid & 63;
  if (tid < NK) { snsh[tid] = sidx[s * NK + tid]; sdsh[tid] = sdist[s * NK + tid]; }
  if (tid == 0) s_max = 0;
  {
    const float4* src4 = (const float4*)(L + (size_t)s * N_PTS);
    float4* dst4 = (float4*)Lrow;
    for (int c = tid; c < N_PTS / 4; c += 256) dst4[c] = src4[c];
  }
  __syncthreads();

  float sd[NK];
#pragma unroll
  for (int i = 0; i < NK; ++i) sd[i] = sdsh[i];
  const float* __restrict__ Arow[NK];
#pragma unroll
  for (int i = 0; i < NK; ++i) Arow[i] = L + (size_t)snsh[i] * N_PTS;
  volatile unsigned int* vmax = &s_max;

  // ---- (a) seed: per wave, exact max of its top-Lsr column ----
  {
    unsigned long long bk = 0ull;
#pragma unroll
    for (int k = 0; k < N_PTS / 256; ++k) {
      const int r = tid + k * 256;
      unsigned long long key =
          (((unsigned long long)__float_as_uint(Lrow[r])) << 32) | (unsigned)r;
      if (key > bk) bk = key;                 // Lrow >= 0: bit order == value order
    }
#pragma unroll
    for (int msk = 32; msk >= 1; msk >>= 1) {
      unsigned long long o = shflxor64(bk, msk);
      if (o > bk) bk = o;
    }
    const int rwin = (int)(bk & 0xFFFFFFFFull);
    const float Lsr = Lrow[rwin];
    unsigned int vb = 0;
    if (lane < NK * NK) {
      const int i = lane / NK, j = lane - i * NK;
      float diff = __fsub_rn(sdsh[i], rdist[rwin * NK + j]);  // frozen chain
      float dsq  = __fmul_rn(diff, diff);
      if (dsq < 0.0101f) {
        float q    = __fdiv_rn(dsq, 0.01f);
        float temp = fmaxf(__fsub_rn(1.0f, q), 0.0f);
        if (temp > 0.0f) {
          float ub = __fmul_rn(Lsr, temp);
          float a  = L[(size_t)snsh[i] * N_PTS + ridx[rwin * NK + j]];
          float v  = __fmul_rn(ub, a);
          if (v > 0.0f) vb = __float_as_uint(v);
        }
      }
    }
#pragma unroll
    for (int msk = 32; msk >= 1; msk >>= 1) {
      unsigned int o = (unsigned)__shfl_xor((int)vb, msk);
      if (o > vb) vb = o;
    }
    if (lane == 0 && vb > 0u) atomicMax(&s_max, vb);
  }

  // ---- main loop: chain-broken snapshot-gated column evaluation ----
  unsigned int lmax = *vmax;                   // one volatile read post-seed
#pragma unroll 1
  for (int k = 0; k < N_PTS / 256; ++k) {
    const int r = tid + k * 256;
    { unsigned int sm = *vmax; if (sm > lmax) lmax = sm; }   // per-iter refresh
    const float Lsr = Lrow[r];
    const float lmaxf = __uint_as_float(lmax);
    if (Lsr <= lmaxf) continue;                // v <= Lsr <= smax
    float rd[NK]; int rn[NK];
#pragma unroll
    for (int j = 0; j < NK; ++j) { rd[j] = rdist[r * NK + j]; rn[j] = ridx[r * NK + j]; }
    float vcol = 0.0f;                         // column max of exact v's
#pragma unroll
    for (int i = 0; i < NK; ++i) {
#pragma unroll
      for (int j = 0; j < NK; ++j) {
        float diff = __fsub_rn(sd[i], rd[j]);
        float dsq  = __fmul_rn(diff, diff);
        if (dsq >= 0.0101f) continue;                    // temp provably 0
        float ts   = __builtin_fmaf(dsq, -99.0f, 1.0f);  // >= temp (exact)
        if (__fmul_rn(Lsr, ts) <= lmaxf) continue;       // div-free pre-gate
        float q    = __fdiv_rn(dsq, 0.01f);
        float temp = fmaxf(__fsub_rn(1.0f, q), 0.0f);
        if (temp <= 0.0f) continue;
        float ub   = __fmul_rn(Lsr, temp);               // frozen inner term
        if (ub <= lmaxf) continue;
        float v = __fmul_rn(ub, Arow[i][rn[j]]);         // frozen chain; gather
        vcol = fmaxf(vcol, v);                           // no lmax in the chain
      }
    }
    if (vcol > __uint_as_float(lmax)) {
      lmax = __float_as_uint(vcol);
      atomicMax(&s_max, lmax);
    }
  }
  __syncthreads();
  if (tid == 0) rowmax[s] = s_max;
}

// ---------------- threshold: T = 512th-largest row max; zero counter ---------
// count(v >= T) >= 512 guaranteed: each of the top-512 rows contributes >= 1.
__global__ __launch_bounds__(1024) void thresh_kernel(
    const unsigned int* __restrict__ rowmax, unsigned int* __restrict__ counters) {
  __shared__ unsigned int a[N_PTS];
  const int tid = threadIdx.x;
  for (int t = tid; t < N_PTS; t += 1024) a[t] = rowmax[t];
  __syncthreads();
  for (int k2 = 2; k2 <= N_PTS; k2 <<= 1) {
    for (int j2 = k2 >> 1; j2 > 0; j2 >>= 1) {
      for (int e = 0; e < N_PTS / 1024; ++e) {
        int i = tid + e * 1024;
        int pj = i ^ j2;
        if (pj > i) {
          bool blk = ((i & k2) == 0);
          unsigned int x = a[i], y = a[pj];
          if (blk ? (x < y) : (x > y)) { a[i] = y; a[pj] = x; }
        }
      }
      __syncthreads();
    }
  }
  if (tid == 0) {
    counters[3] = a[TOPK - 1];
    counters[0] = 0;
  }
}

// ---------------- pass 2: collect, static Lsr < T rejection ------------------
__global__ __launch_bounds__(256) void collect_kernel(
    const float* __restrict__ L,
    const int* __restrict__ sidx, const float* __restrict__ sdist,
    const int* __restrict__ ridx, const float* __restrict__ rdist,
    const unsigned int* __restrict__ rowmax,
    unsigned int* __restrict__ counters, uint64_t* __restrict__ cand,
    unsigned int cap) {
  __shared__ float Lrow[N_PTS];
  __shared__ float sdsh[NK];
  __shared__ int   snsh[NK];
  const int s = blockIdx.x, tid = threadIdx.x;
  const unsigned int T = counters[3];
  if (rowmax[s] < T) return;            // uniform: whole row can't contribute
  const float T_f = __uint_as_float(T);
  if (tid < NK) { snsh[tid] = sidx[s * NK + tid]; sdsh[tid] = sdist[s * NK + tid]; }
  {
    const float4* src4 = (const float4*)(L + (size_t)s * N_PTS);
    float4* dst4 = (float4*)Lrow;
    for (int c = tid; c < N_PTS / 4; c += 256) dst4[c] = src4[c];
  }
  __syncthreads();

  float sd[NK];
#pragma unroll
  for (int i = 0; i < NK; ++i) sd[i] = sdsh[i];

  for (int r = tid; r < N_PTS; r += 256) {
    float Lsr = Lrow[r];
    if (Lsr < T_f) continue;                             // v <= Lsr < T
    float rd[NK]; int rn[NK];
#pragma unroll
    for (int j = 0; j < NK; ++j) { rd[j] = rdist[r * NK + j]; rn[j] = ridx[r * NK + j]; }
#pragma unroll
    for (int i = 0; i < NK; ++i) {
      const float* __restrict__ Arow = L + (size_t)snsh[i] * N_PTS;
#pragma unroll
      for (int j = 0; j < NK; ++j) {
        float diff = __fsub_rn(sd[i], rd[j]);
        float dsq  = __fmul_rn(diff, diff);
        if (dsq >= 0.0101f) continue;
        float ts   = __builtin_fmaf(dsq, -99.0f, 1.0f);  // >= temp (exact)
        float ubt  = __fmul_rn(Lsr, ts);                 // >= ub >= v
        if (ubt < T_f) continue;                         // div-free pre-gate
        float q    = __fdiv_rn(dsq, 0.01f);
        float temp = fmaxf(__fsub_rn(1.0f, q), 0.0f);
        if (temp <= 0.0f) continue;
        float ub   = __fmul_rn(Lsr, temp);
        if (ub < T_f) continue;                          // v <= ub < T
        float v = __fmul_rn(ub, Arow[rn[j]]);            // frozen chain
        unsigned int vb = __float_as_uint(v);
        if (v > 0.0f && vb >= T) {
          unsigned int pos = atomicAdd(&counters[0], 1u);
          if (pos < cap) {
            unsigned int idx = ((unsigned int)s * (unsigned int)N_PTS
                                + (unsigned int)r) * 25u
                             + (unsigned int)i * 5u + (unsigned int)j;
            cand[pos] = (((uint64_t)vb) << 32) | (uint64_t)((uint32_t)(~idx));
          }
        }
      }
    }
  }
}

// ---------------- exact top-512: byte radix-select + bitonic sort ------------
// r5: (1) 16-way wave-split histogram h[16][257] (pad => distinct banks per
//     copy) kills the same-address LDS-atomic serialization (all values in
//     (0.5,1) share top byte 0x3F). (2) serial 256-bin scan on tid0 (8 x
//     ~256 chained LDS reads) replaced by a wave-0 register suffix-scan:
//     lane l owns bins 4l..4l+3, 6-step shfl suffix sum, unique crossing
//     lane writes sh_prefix/sh_k. Semantics identical to the serial loop
//     (incl. degenerate no-crossing fallback: chosen=0, sh_k unchanged).
__global__ __launch_bounds__(1024) void select_kernel(
    const uint64_t* __restrict__ cand, const unsigned int* __restrict__ counters,
    const int* __restrict__ sidx, const int* __restrict__ ridx,
    int* __restrict__ out, unsigned int cap) {
  __shared__ unsigned int h[16][257];          // wave-split histogram, padded
  __shared__ uint64_t topk[TOPK];
  __shared__ unsigned int cnt2;
  __shared__ uint64_t sh_prefix;
  __shared__ unsigned int sh_k;
  const int tid = threadIdx.x;
  const int wv = tid >> 6;
  unsigned int n = counters[0];
  if (n > cap) n = cap;
  if (tid == 0) { sh_prefix = 0; sh_k = TOPK; cnt2 = 0; }
  unsigned int* hflat = &h[0][0];

  for (int byte = 7; byte >= 0; --byte) {
    for (int t = tid; t < 16 * 257; t += 1024) hflat[t] = 0;
    __syncthreads();
    const uint64_t prefix = sh_prefix;
    const uint64_t mask = (byte == 7) ? 0ull : (~0ull << (8 * (byte + 1)));
    for (unsigned int i = tid; i < n; i += 1024) {
      uint64_t key = cand[i];
      if ((key & mask) == prefix)
        atomicAdd(&h[wv][(unsigned int)(key >> (8 * byte)) & 255u], 1u);
    }
    __syncthreads();
    if (tid < 64) {                            // wave 0: parallel bin select
      const int b0i = tid * 4;
      unsigned int c0 = 0, c1 = 0, c2 = 0, c3 = 0;
#pragma unroll
      for (int w = 0; w < 16; ++w) {
        c0 += h[w][b0i + 0]; c1 += h[w][b0i + 1];
        c2 += h[w][b0i + 2]; c3 += h[w][b0i + 3];
      }
      const unsigned int S = c0 + c1 + c2 + c3;
      unsigned int si = S;                     // inclusive suffix over lanes
#pragma unroll
      for (int off = 1; off < 64; off <<= 1) {
        unsigned int o = (unsigned)__shfl_down((int)si, off);
        si += (tid + off < 64) ? o : 0u;
      }
      const unsigned int SE = si - S;          // suffix-exclusive of this lane
      const unsigned int k = sh_k;
      const unsigned int s3 = SE + c3;         // SI(b0i+3)
      const unsigned int s2 = s3 + c2;
      const unsigned int s1 = s2 + c1;
      const unsigned int s0 = s1 + c0;         // SI(b0i+0)
      int b = -1; unsigned int kn = 0;
      if      (s0 >= k && s1 < k) { b = b0i + 0; kn = k - s1; }
      else if (s1 >= k && s2 < k) { b = b0i + 1; kn = k - s2; }
      else if (s2 >= k && s3 < k) { b = b0i + 2; kn = k - s3; }
      else if (s3 >= k && SE < k) { b = b0i + 3; kn = k - SE; }
      unsigned long long bal = __ballot(b >= 0);
      if (b >= 0) {
        sh_prefix = prefix | (((uint64_t)(unsigned)b) << (8 * byte));
        sh_k = kn;
      } else if (tid == 0 && bal == 0ull) {
        sh_prefix = prefix;                    // degenerate: chosen=0, k kept
      }
    }
    __syncthreads();
  }
  const uint64_t kstar = sh_prefix;

  for (int t = tid; t < TOPK; t += 1024) topk[t] = 0;
  __syncthreads();
  for (unsigned int i = tid; i < n; i += 1024) {
    uint64_t key = cand[i];
    if (key >= kstar) {
      unsigned int pos = atomicAdd(&cnt2, 1u);
      if (pos < TOPK) topk[pos] = key;
    }
  }
  __syncthreads();

  for (int k2 = 2; k2 <= TOPK; k2 <<= 1) {
    for (int j2 = k2 >> 1; j2 > 0; j2 >>= 1) {
      if (tid < TOPK) {
        int ixj = tid ^ j2;
        if (ixj > tid) {
          bool asc = ((tid & k2) == 0);
          uint64_t a = topk[tid], b = topk[ixj];
          if (asc ? (a < b) : (a > b)) { topk[tid] = b; topk[ixj] = a; }
        }
      }
      __syncthreads();
    }
  }

  if (tid < TOPK) {
    uint64_t key = topk[tid];
    unsigned int idx = ~((unsigned int)key);
    if (idx >= 104857600u) idx = 0;           // safety clamp (degenerate only)
    unsigned int s   = idx / 51200u;          // n_r*K*K = 2048*25
    unsigned int rem = idx % 51200u;
    unsigned int r   = rem / 25u;
    unsigned int sij = rem % 25u;
    out[0 * TOPK + tid] = (int)s;                       // first_node_src
    out[1 * TOPK + tid] = (int)r;                       // first_node_ref
    out[2 * TOPK + tid] = sidx[s * NK + sij / 5u];      // second_node_src
    out[3 * TOPK + tid] = ridx[r * NK + sij % 5u];      // second_node_ref
  }
}

extern "C" void kernel_launch(void* const* d_in, const int* in_sizes, int n_in,
                              void* d_out, int out_size, void* d_ws, size_t ws_size,
                              hipStream_t stream) {
  const float* src = (const float*)d_in[0];
  const float* ref = (const float*)d_in[1];
  const float* L   = (const float*)d_in[2];
  char* ws = (char*)d_ws;
  int*          sidx  = (int*)(ws + OFF_SIDX);
  float*        sdist = (float*)(ws + OFF_SDIST);
  int*          ridx  = (int*)(ws + OFF_RIDX);
  float*        rdist = (float*)(ws + OFF_RDIST);
  unsigned int* rmax  = (unsigned int*)(ws + OFF_RMAX);
  unsigned int* cnts  = (unsigned int*)(ws + OFF_CNT);
  uint64_t*     cand  = (uint64_t*)(ws + OFF_CAND);
  int*          out   = (int*)d_out;

  unsigned int cap = 0;
  if (ws_size > (size_t)OFF_CAND + 8) {
    size_t c = (ws_size - (size_t)OFF_CAND) / 8;
    cap = (c > CAP_MAX) ? CAP_MAX : (unsigned int)c;
  }

  knn_kernel<<<512, 256, 0, stream>>>(src, ref, sidx, sdist, ridx, rdist);
  rowmax_kernel<<<N_PTS, 256, 0, stream>>>(L, sidx, sdist, ridx, rdist, rmax);
  thresh_kernel<<<1, 1024, 0, stream>>>(rmax, cnts);
  collect_kernel<<<N_PTS, 256, 0, stream>>>(L, sidx, sdist, ridx, rdist, rmax, cnts, cand, cap);
  select_kernel<<<1, 1024, 0, stream>>>(cand, cnts, sidx, ridx, out, cap);
}

// Round 6
// 186.968 us; speedup vs baseline: 1.7402x; 1.0725x over previous
//
#include <hip/hip_runtime.h>
#include <stdint.h>

#define N_PTS 2048
#define NK 5
#define TOPK 512
#define CAP_MAX 262144u

// frozen arithmetic (r9-verified bit-exact vs np oracle):
//   d2 = fma(dz,dz, fma(dx,dx, dy*dy)); d = sqrt(max(d2,0))
//   q = fdiv(diff*diff, 0.01f); temp = max(1-q,0); v = (L*temp)*A
// tie rule: value desc, flat idx asc (key (vb<<32)|~idx descending)
// rejection bounds (exact under rounding, temp<=1, A<1, L>=0, A>=0):
//   v <= fmul_rn(Lsr,temp) <= Lsr
// div-free cell pre-gate (exact, RN-monotone):
//   q = RN(dsq/0.01f) >= 99.9999*dsq  =>  1-q <= 1-99*dsq
//   temp = RN(1-q) <= RN(1-99*dsq) = fma(dsq,-99,1) = ts
//   => ubt = RN(Lsr*ts) >= RN(Lsr*temp) = ub >= v   (all operands >= 0)
// latency rule (r4): never place a gather-dependent value in the gate of the
//   next gather — gate on snapshot lmax, combine v's with fmaxf afterwards.
// serialization rule (r5): no serial per-bin scans on one lane; no
//   clustered-key LDS atomic histograms without wave-split.
// threshold relaxation (r6): T need NOT be the exact 512th rowmax. Any
//   T' <= T_exact gives a candidate SUPERSET; select's exact global top-512
//   over a superset is bit-identical. Sufficient conditions:
//   (a) T' = 512th largest lb[s] where lb[s] is an exactly-computed cell
//       value of row s => each top-512-lb row contributes >= 1 cell >= T'.
//   (b) collect scans ALL rows, gating columns on Lsr < T' (v <= Lsr) =>
//       every cell v >= T' is collected. No row-skip allowed.

// ws layout (bytes):
//      0  src_ne_idx   int[10240]    (40960)
//  40960  src_ne_dist  f32[10240]    (40960)
//  81920  ref_ne_idx   int[10240]    (40960)
// 122880  ref_ne_dist  f32[10240]    (40960)
// 163840  lb           uint[2048]    (8192)   (per-row lower bound, exact cell)
// 172032  counters     uint[8]       (32)   [0]=cand_count [3]=T'
// 172064  cand         uint64[cap]
#define OFF_SIDX   0
#define OFF_SDIST  40960
#define OFF_RIDX   81920
#define OFF_RDIST  122880
#define OFF_RMAX   163840
#define OFF_CNT    172032
#define OFF_CAND   172064

__device__ __forceinline__ unsigned long long shflxor64(unsigned long long v, int mask) {
  unsigned lo = (unsigned)v, hi = (unsigned)(v >> 32);
  lo = (unsigned)__shfl_xor((int)lo, mask);
  hi = (unsigned)__shfl_xor((int)hi, mask);
  return ((unsigned long long)hi << 32) | lo;
}

// ---------------- KNN: 512 blocks, 8 points/block, 32 lanes/point ------------
__global__ __launch_bounds__(256) void knn_kernel(
    const float* __restrict__ src, const float* __restrict__ ref,
    int* __restrict__ sidx, float* __restrict__ sdist,
    int* __restrict__ ridx, float* __restrict__ rdist) {
  __shared__ float sx[N_PTS], sy[N_PTS], sz[N_PTS];
  const bool is_ref = blockIdx.x >= 256;
  const float* pts = is_ref ? ref : src;
  int*   oidx  = is_ref ? ridx : sidx;
  float* odist = is_ref ? rdist : sdist;
  const int blk = is_ref ? (blockIdx.x - 256) : blockIdx.x;

  for (int t = threadIdx.x; t < N_PTS; t += 256) {
    sx[t] = pts[3 * t + 0];
    sy[t] = pts[3 * t + 1];
    sz[t] = pts[3 * t + 2];
  }
  __syncthreads();

  const int p = blk * 8 + (threadIdx.x >> 5);
  const int u = threadIdx.x & 31;
  const float px = sx[p], py = sy[p], pz = sz[p];

  unsigned long long best[6];
#pragma unroll
  for (int k = 0; k < 6; ++k) best[k] = ~0ull;

  for (int j = u; j < N_PTS; j += 32) {
    float dx = __fsub_rn(px, sx[j]);
    float dy = __fsub_rn(py, sy[j]);
    float dz = __fsub_rn(pz, sz[j]);
    float d2 = __builtin_fmaf(dz, dz,
                 __builtin_fmaf(dx, dx, __fmul_rn(dy, dy)));
    float d = __fsqrt_rn(fmaxf(d2, 0.0f));
    unsigned long long key = (((unsigned long long)__float_as_uint(d)) << 32)
                           | (unsigned)j;
    if (key < best[5]) {
      best[5] = key;
#pragma unroll
      for (int k = 5; k >= 1; --k)
        if (best[k] < best[k - 1]) {
          unsigned long long t = best[k]; best[k] = best[k - 1]; best[k - 1] = t;
        }
    }
  }

  int h = 0;
  unsigned long long win[6];
#pragma unroll
  for (int round = 0; round < 6; ++round) {
    unsigned long long my = (h < 6) ? best[h] : ~0ull;
    unsigned long long m = my;
#pragma unroll
    for (int msk = 16; msk >= 1; msk >>= 1) {
      unsigned long long o = shflxor64(m, msk);
      if (o < m) m = o;
    }
    win[round] = m;
    if (my == m) ++h;
  }

  if (u == 0) {
#pragma unroll
    for (int m = 1; m <= NK; ++m) {     // drop win[0] == self (d = 0)
      oidx[p * NK + m - 1]  = (int)(win[m] & 0xFFFFFFFFull);
      odist[p * NK + m - 1] = __uint_as_float((unsigned)(win[m] >> 32));
    }
  }
}

// ---------------- pass 1: per-row LOWER BOUND (seed only, no exact max) ------
// Streams the L-row into registers (coalesced float4, no LDS staging, no
// barriers in the scan). Per wave: top-2 Lsr columns (thread-top-2 + 2-round
// wave reduce), each evaluated exactly with the FROZEN chain on 25 lanes.
// lb[s] = max of the 8 evaluated columns' cell maxima — an exactly-computed
// cell value of row s (or 0). See r6 relaxation proof in header.
__global__ __launch_bounds__(256) void lowb_kernel(
    const float* __restrict__ L,
    const int* __restrict__ sidx, const float* __restrict__ sdist,
    const int* __restrict__ ridx, const float* __restrict__ rdist,
    unsigned int* __restrict__ lb) {
  __shared__ float sdsh[NK];
  __shared__ int   snsh[NK];
  __shared__ unsigned int s_max;
  const int s = blockIdx.x, tid = threadIdx.x;
  const int lane = tid & 63;
  if (tid < NK) { snsh[tid] = sidx[s * NK + tid]; sdsh[tid] = sdist[s * NK + tid]; }
  if (tid == 0) s_max = 0;
  const float* __restrict__ Lg = L + (size_t)s * N_PTS;

  // per-thread top-2 over its 8 contiguous columns (2x float4, coalesced)
  unsigned long long b0 = 0ull, b1 = 0ull;
  {
    const float4* Lg4 = (const float4*)Lg;
    float4 A0 = Lg4[2 * tid], A1 = Lg4[2 * tid + 1];
    float lv[8] = {A0.x, A0.y, A0.z, A0.w, A1.x, A1.y, A1.z, A1.w};
#pragma unroll
    for (int e = 0; e < 8; ++e) {
      unsigned long long key =
          (((unsigned long long)__float_as_uint(lv[e])) << 32)
          | (unsigned)(tid * 8 + e);           // L >= 0: bit order == value order
      if (key > b0) { b1 = b0; b0 = key; } else if (key > b1) b1 = key;
    }
  }
  __syncthreads();                             // sdsh/snsh ready

  int h = 0;
  for (int round = 0; round < 2; ++round) {
    unsigned long long my = (h == 0) ? b0 : ((h == 1) ? b1 : 0ull);
    unsigned long long w = my;
#pragma unroll
    for (int msk = 32; msk >= 1; msk >>= 1) {
      unsigned long long o = shflxor64(w, msk);
      if (o > w) w = o;
    }
    if (my == w && w != 0ull) ++h;             // unique keys (r embedded)
    if ((unsigned)(w >> 32) == 0u) continue;
    const int rwin = (int)(w & 0xFFFFFFFFull);
    const float Lsr = __uint_as_float((unsigned)(w >> 32));
    unsigned int vb = 0;
    if (lane < NK * NK) {
      const int i = lane / NK, j = lane - i * NK;
      float diff = __fsub_rn(sdsh[i], rdist[rwin * NK + j]);  // frozen chain
      float dsq  = __fmul_rn(diff, diff);
      if (dsq < 0.0101f) {
        float q    = __fdiv_rn(dsq, 0.01f);
        float temp = fmaxf(__fsub_rn(1.0f, q), 0.0f);
        if (temp > 0.0f) {
          float ub = __fmul_rn(Lsr, temp);
          float a  = L[(size_t)snsh[i] * N_PTS + ridx[rwin * NK + j]];
          float v  = __fmul_rn(ub, a);
          if (v > 0.0f) vb = __float_as_uint(v);
        }
      }
    }
#pragma unroll
    for (int msk = 32; msk >= 1; msk >>= 1) {
      unsigned int o = (unsigned)__shfl_xor((int)vb, msk);
      if (o > vb) vb = o;
    }
    if (lane == 0 && vb > 0u) atomicMax(&s_max, vb);
  }
  __syncthreads();
  if (tid == 0) lb[s] = s_max;
}

// ---------------- threshold: T' = 512th-largest lb; zero counter -------------
// count(v >= T') >= 512: each of the top-512-lb rows contributes >= 1 cell
// (its lb-achieving cell, an exact value >= T').
__global__ __launch_bounds__(1024) void thresh_kernel(
    const unsigned int* __restrict__ lb, unsigned int* __restrict__ counters) {
  __shared__ unsigned int a[N_PTS];
  const int tid = threadIdx.x;
  for (int t = tid; t < N_PTS; t += 1024) a[t] = lb[t];
  __syncthreads();
  for (int k2 = 2; k2 <= N_PTS; k2 <<= 1) {
    for (int j2 = k2 >> 1; j2 > 0; j2 >>= 1) {
      for (int e = 0; e < N_PTS / 1024; ++e) {
        int i = tid + e * 1024;
        int pj = i ^ j2;
        if (pj > i) {
          bool blk = ((i & k2) == 0);
          unsigned int x = a[i], y = a[pj];
          if (blk ? (x < y) : (x > y)) { a[i] = y; a[pj] = x; }
        }
      }
      __syncthreads();
    }
  }
  if (tid == 0) {
    counters[3] = a[TOPK - 1];
    counters[0] = 0;
  }
}

// ---------------- pass 2: collect over ALL rows, static Lsr < T' gate --------
// r6: no row-skip (required for completeness — see header). No LDS Lrow:
// each thread holds its 8 contiguous Lsr in registers (2x float4, coalesced).
// Static threshold => no volatile polling, no atomicMax warm-up. Frozen cell
// chain + div-free pre-gate identical to r5.
__global__ __launch_bounds__(256) void collect_kernel(
    const float* __restrict__ L,
    const int* __restrict__ sidx, const float* __restrict__ sdist,
    const int* __restrict__ ridx, const float* __restrict__ rdist,
    unsigned int* __restrict__ counters, uint64_t* __restrict__ cand,
    unsigned int cap) {
  __shared__ float sdsh[NK];
  __shared__ int   snsh[NK];
  const int s = blockIdx.x, tid = threadIdx.x;
  const unsigned int T = counters[3];
  const float T_f = __uint_as_float(T);
  if (tid < NK) { snsh[tid] = sidx[s * NK + tid]; sdsh[tid] = sdist[s * NK + tid]; }
  const float* __restrict__ Lg = L + (size_t)s * N_PTS;
  const float4* Lg4 = (const float4*)Lg;
  float4 A0 = Lg4[2 * tid], A1 = Lg4[2 * tid + 1];
  float lv[8] = {A0.x, A0.y, A0.z, A0.w, A1.x, A1.y, A1.z, A1.w};
  __syncthreads();

  float sd[NK];
#pragma unroll
  for (int i = 0; i < NK; ++i) sd[i] = sdsh[i];

#pragma unroll
  for (int e = 0; e < 8; ++e) {
    const float Lsr = lv[e];
    if (Lsr < T_f) continue;                             // v <= Lsr < T'
    const int r = tid * 8 + e;
    float rd[NK]; int rn[NK];
#pragma unroll
    for (int j = 0; j < NK; ++j) { rd[j] = rdist[r * NK + j]; rn[j] = ridx[r * NK + j]; }
#pragma unroll
    for (int i = 0; i < NK; ++i) {
      const float* __restrict__ Arow = L + (size_t)snsh[i] * N_PTS;
#pragma unroll
      for (int j = 0; j < NK; ++j) {
        float diff = __fsub_rn(sd[i], rd[j]);
        float dsq  = __fmul_rn(diff, diff);
        if (dsq >= 0.0101f) continue;
        float ts   = __builtin_fmaf(dsq, -99.0f, 1.0f);  // >= temp (exact)
        float ubt  = __fmul_rn(Lsr, ts);                 // >= ub >= v
        if (ubt < T_f) continue;                         // div-free pre-gate
        float q    = __fdiv_rn(dsq, 0.01f);
        float temp = fmaxf(__fsub_rn(1.0f, q), 0.0f);
        if (temp <= 0.0f) continue;
        float ub   = __fmul_rn(Lsr, temp);
        if (ub < T_f) continue;                          // v <= ub < T'
        float v = __fmul_rn(ub, Arow[rn[j]]);            // frozen chain
        unsigned int vb = __float_as_uint(v);
        if (v > 0.0f && vb >= T) {
          unsigned int pos = atomicAdd(&counters[0], 1u);
          if (pos < cap) {
            unsigned int idx = ((unsigned int)s * (unsigned int)N_PTS
                                + (unsigned int)r) * 25u
                             + (unsigned int)i * 5u + (unsigned int)j;
            cand[pos] = (((uint64_t)vb) << 32) | (uint64_t)((uint32_t)(~idx));
          }
        }
      }
    }
  }
}

// ---------------- exact top-512: byte radix-select + bitonic sort ------------
// r5: 16-way wave-split histogram + wave-0 register suffix-scan bin select.
__global__ __launch_bounds__(1024) void select_kernel(
    const uint64_t* __restrict__ cand, const unsigned int* __restrict__ counters,
    const int* __restrict__ sidx, const int* __restrict__ ridx,
    int* __restrict__ out, unsigned int cap) {
  __shared__ unsigned int h[16][257];          // wave-split histogram, padded
  __shared__ uint64_t topk[TOPK];
  __shared__ unsigned int cnt2;
  __shared__ uint64_t sh_prefix;
  __shared__ unsigned int sh_k;
  const int tid = threadIdx.x;
  const int wv = tid >> 6;
  unsigned int n = counters[0];
  if (n > cap) n = cap;
  if (tid == 0) { sh_prefix = 0; sh_k = TOPK; cnt2 = 0; }
  unsigned int* hflat = &h[0][0];

  for (int byte = 7; byte >= 0; --byte) {
    for (int t = tid; t < 16 * 257; t += 1024) hflat[t] = 0;
    __syncthreads();
    const uint64_t prefix = sh_prefix;
    const uint64_t mask = (byte == 7) ? 0ull : (~0ull << (8 * (byte + 1)));
    for (unsigned int i = tid; i < n; i += 1024) {
      uint64_t key = cand[i];
      if ((key & mask) == prefix)
        atomicAdd(&h[wv][(unsigned int)(key >> (8 * byte)) & 255u], 1u);
    }
    __syncthreads();
    if (tid < 64) {                            // wave 0: parallel bin select
      const int b0i = tid * 4;
      unsigned int c0 = 0, c1 = 0, c2 = 0, c3 = 0;
#pragma unroll
      for (int w = 0; w < 16; ++w) {
        c0 += h[w][b0i + 0]; c1 += h[w][b0i + 1];
        c2 += h[w][b0i + 2]; c3 += h[w][b0i + 3];
      }
      const unsigned int S = c0 + c1 + c2 + c3;
      unsigned int si = S;                     // inclusive suffix over lanes
#pragma unroll
      for (int off = 1; off < 64; off <<= 1) {
        unsigned int o = (unsigned)__shfl_down((int)si, off);
        si += (tid + off < 64) ? o : 0u;
      }
      const unsigned int SE = si - S;          // suffix-exclusive of this lane
      const unsigned int k = sh_k;
      const unsigned int s3 = SE + c3;         // SI(b0i+3)
      const unsigned int s2 = s3 + c2;
      const unsigned int s1 = s2 + c1;
      const unsigned int s0 = s1 + c0;         // SI(b0i+0)
      int b = -1; unsigned int kn = 0;
      if      (s0 >= k && s1 < k) { b = b0i + 0; kn = k - s1; }
      else if (s1 >= k && s2 < k) { b = b0i + 1; kn = k - s2; }
      else if (s2 >= k && s3 < k) { b = b0i + 2; kn = k - s3; }
      else if (s3 >= k && SE < k) { b = b0i + 3; kn = k - SE; }
      unsigned long long bal = __ballot(b >= 0);
      if (b >= 0) {
        sh_prefix = prefix | (((uint64_t)(unsigned)b) << (8 * byte));
        sh_k = kn;
      } else if (tid == 0 && bal == 0ull) {
        sh_prefix = prefix;                    // degenerate: chosen=0, k kept
      }
    }
    __syncthreads();
  }
  const uint64_t kstar = sh_prefix;

  for (int t = tid; t < TOPK; t += 1024) topk[t] = 0;
  __syncthreads();
  for (unsigned int i = tid; i < n; i += 1024) {
    uint64_t key = cand[i];
    if (key >= kstar) {
      unsigned int pos = atomicAdd(&cnt2, 1u);
      if (pos < TOPK) topk[pos] = key;
    }
  }
  __syncthreads();

  for (int k2 = 2; k2 <= TOPK; k2 <<= 1) {
    for (int j2 = k2 >> 1; j2 > 0; j2 >>= 1) {
      if (tid < TOPK) {
        int ixj = tid ^ j2;
        if (ixj > tid) {
          bool asc = ((tid & k2) == 0);
          uint64_t a = topk[tid], b = topk[ixj];
          if (asc ? (a < b) : (a > b)) { topk[tid] = b; topk[ixj] = a; }
        }
      }
      __syncthreads();
    }
  }

  if (tid < TOPK) {
    uint64_t key = topk[tid];
    unsigned int idx = ~((unsigned int)key);
    if (idx >= 104857600u) idx = 0;           // safety clamp (degenerate only)
    unsigned int s   = idx / 51200u;          // n_r*K*K = 2048*25
    unsigned int rem = idx % 51200u;
    unsigned int r   = rem / 25u;
    unsigned int sij = rem % 25u;
    out[0 * TOPK + tid] = (int)s;                       // first_node_src
    out[1 * TOPK + tid] = (int)r;                       // first_node_ref
    out[2 * TOPK + tid] = sidx[s * NK + sij / 5u];      // second_node_src
    out[3 * TOPK + tid] = ridx[r * NK + sij % 5u];      // second_node_ref
  }
}

extern "C" void kernel_launch(void* const* d_in, const int* in_sizes, int n_in,
                              void* d_out, int out_size, void* d_ws, size_t ws_size,
                              hipStream_t stream) {
  const float* src = (const float*)d_in[0];
  const float* ref = (const float*)d_in[1];
  const float* L   = (const float*)d_in[2];
  char* ws = (char*)d_ws;
  int*          sidx  = (int*)(ws + OFF_SIDX);
  float*        sdist = (float*)(ws + OFF_SDIST);
  int*          ridx  = (int*)(ws + OFF_RIDX);
  float*        rdist = (float*)(ws + OFF_RDIST);
  unsigned int* lb    = (unsigned int*)(ws + OFF_RMAX);
  unsigned int* cnts  = (unsigned int*)(ws + OFF_CNT);
  uint64_t*     cand  = (uint64_t*)(ws + OFF_CAND);
  int*          out   = (int*)d_out;

  unsigned int cap = 0;
  if (ws_size > (size_t)OFF_CAND + 8) {
    size_t c = (ws_size - (size_t)OFF_CAND) / 8;
    cap = (c > CAP_MAX) ? CAP_MAX : (unsigned int)c;
  }

  knn_kernel<<<512, 256, 0, stream>>>(src, ref, sidx, sdist, ridx, rdist);
  lowb_kernel<<<N_PTS, 256, 0, stream>>>(L, sidx, sdist, ridx, rdist, lb);
  thresh_kernel<<<1, 1024, 0, stream>>>(lb, cnts);
  collect_kernel<<<N_PTS, 256, 0, stream>>>(L, sidx, sdist, ridx, rdist, cnts, cand, cap);
  select_kernel<<<1, 1024, 0, stream>>>(cand, cnts, sidx, ridx, out, cap);
}

// Round 9
// 173.799 us; speedup vs baseline: 1.8721x; 1.0758x over previous
//
#include <hip/hip_runtime.h>
#include <stdint.h>

#define N_PTS 2048
#define NK 5
#define TOPK 512
#define CAP_MAX 262144u

// frozen arithmetic (r9-verified bit-exact vs np oracle):
//   d2 = fma(dz,dz, fma(dx,dx, dy*dy)); d = sqrt(max(d2,0))
//   q = fdiv(diff*diff, 0.01f); temp = max(1-q,0); v = (L*temp)*A
// tie rule: value desc, flat idx asc (key (vb<<32)|~idx descending)
// rejection bounds (exact under rounding, temp<=1, A<1, L>=0, A>=0):
//   v <= fmul_rn(Lsr,temp) <= Lsr
// div-free cell pre-gate (exact, RN-monotone):
//   temp <= fma(dsq,-99,1) = ts  =>  RN(Lsr*ts) >= ub >= v
// latency rule (r4): no gather-dependent value in the gate of the next gather.
// serialization rule (r5): no serial per-bin scans on one lane; no
//   clustered-key LDS atomic histograms without wave-split.
// threshold relaxation (r6): any deterministic T' <= (512th-largest lb) gives
//   a candidate superset; select's exact top-512 over a superset is
//   bit-identical. lb[s] must be an exactly-computed cell value of row s;
//   collect must scan ALL rows gated only on Lsr (no row-skip).
// launch rule (r7): no cooperative launch / grid.sync under this harness —
//   deterministic container failure.
// anchor rule (r9): after a container failure, re-establish a known-good
//   baseline (minimal delta from last passing kernel) before retrying the
//   failed structural change.

// ws layout (bytes):
//      0  src_ne_idx   int[10240]    (40960)
//  40960  src_ne_dist  f32[10240]    (40960)
//  81920  ref_ne_idx   int[10240]    (40960)
// 122880  ref_ne_dist  f32[10240]    (40960)
// 163840  lb           uint[2048]    (8192)   (per-row lower bound, exact cell)
// 172032  counters     uint[8]       (32)   [0]=cand_count [3]=T'
// 172064  cand         uint64[cap]
#define OFF_SIDX   0
#define OFF_SDIST  40960
#define OFF_RIDX   81920
#define OFF_RDIST  122880
#define OFF_RMAX   163840
#define OFF_CNT    172032
#define OFF_CAND   172064

__device__ __forceinline__ unsigned long long shflxor64(unsigned long long v, int mask) {
  unsigned lo = (unsigned)v, hi = (unsigned)(v >> 32);
  lo = (unsigned)__shfl_xor((int)lo, mask);
  hi = (unsigned)__shfl_xor((int)hi, mask);
  return ((unsigned long long)hi << 32) | lo;
}

// ---------------- KNN: 512 blocks, 8 points/block, 32 lanes/point ------------
__global__ __launch_bounds__(256) void knn_kernel(
    const float* __restrict__ src, const float* __restrict__ ref,
    int* __restrict__ sidx, float* __restrict__ sdist,
    int* __restrict__ ridx, float* __restrict__ rdist) {
  __shared__ float sx[N_PTS], sy[N_PTS], sz[N_PTS];
  const bool is_ref = blockIdx.x >= 256;
  const float* pts = is_ref ? ref : src;
  int*   oidx  = is_ref ? ridx : sidx;
  float* odist = is_ref ? rdist : sdist;
  const int blk = is_ref ? (blockIdx.x - 256) : blockIdx.x;

  for (int t = threadIdx.x; t < N_PTS; t += 256) {
    sx[t] = pts[3 * t + 0];
    sy[t] = pts[3 * t + 1];
    sz[t] = pts[3 * t + 2];
  }
  __syncthreads();

  const int p = blk * 8 + (threadIdx.x >> 5);
  const int u = threadIdx.x & 31;
  const float px = sx[p], py = sy[p], pz = sz[p];

  unsigned long long best[6];
#pragma unroll
  for (int k = 0; k < 6; ++k) best[k] = ~0ull;

  for (int j = u; j < N_PTS; j += 32) {
    float dx = __fsub_rn(px, sx[j]);
    float dy = __fsub_rn(py, sy[j]);
    float dz = __fsub_rn(pz, sz[j]);
    float d2 = __builtin_fmaf(dz, dz,
                 __builtin_fmaf(dx, dx, __fmul_rn(dy, dy)));
    float d = __fsqrt_rn(fmaxf(d2, 0.0f));
    unsigned long long key = (((unsigned long long)__float_as_uint(d)) << 32)
                           | (unsigned)j;
    if (key < best[5]) {
      best[5] = key;
#pragma unroll
      for (int k = 5; k >= 1; --k)
        if (best[k] < best[k - 1]) {
          unsigned long long t = best[k]; best[k] = best[k - 1]; best[k - 1] = t;
        }
    }
  }

  int h = 0;
  unsigned long long win[6];
#pragma unroll
  for (int round = 0; round < 6; ++round) {
    unsigned long long my = (h < 6) ? best[h] : ~0ull;
    unsigned long long m = my;
#pragma unroll
    for (int msk = 16; msk >= 1; msk >>= 1) {
      unsigned long long o = shflxor64(m, msk);
      if (o < m) m = o;
    }
    win[round] = m;
    if (my == m) ++h;
  }

  if (u == 0) {
#pragma unroll
    for (int m = 1; m <= NK; ++m) {     // drop win[0] == self (d = 0)
      oidx[p * NK + m - 1]  = (int)(win[m] & 0xFFFFFFFFull);
      odist[p * NK + m - 1] = __uint_as_float((unsigned)(win[m] >> 32));
    }
  }
}

// ---------------- pass 1: per-row LOWER BOUND (seed only, no exact max) ------
// Streams the L-row into registers (coalesced float4, no LDS staging, no
// barriers in the scan). Per wave: top-3 Lsr columns (thread-top-3 + 3-round
// wave reduce), each evaluated exactly with the FROZEN chain on 25 lanes.
// lb[s] = max of the 12 evaluated columns' cell maxima — an exactly-computed
// cell value of row s (or 0). See r6 relaxation proof in header.
__global__ __launch_bounds__(256) void lowb_kernel(
    const float* __restrict__ L,
    const int* __restrict__ sidx, const float* __restrict__ sdist,
    const int* __restrict__ ridx, const float* __restrict__ rdist,
    unsigned int* __restrict__ lb) {
  __shared__ float sdsh[NK];
  __shared__ int   snsh[NK];
  __shared__ unsigned int s_max;
  const int s = blockIdx.x, tid = threadIdx.x;
  const int lane = tid & 63;
  if (tid < NK) { snsh[tid] = sidx[s * NK + tid]; sdsh[tid] = sdist[s * NK + tid]; }
  if (tid == 0) s_max = 0;
  const float* __restrict__ Lg = L + (size_t)s * N_PTS;

  // per-thread top-3 over its 8 contiguous columns (2x float4, coalesced)
  unsigned long long b0 = 0ull, b1 = 0ull, b2 = 0ull;
  {
    const float4* Lg4 = (const float4*)Lg;
    float4 A0 = Lg4[2 * tid], A1 = Lg4[2 * tid + 1];
    float lv[8] = {A0.x, A0.y, A0.z, A0.w, A1.x, A1.y, A1.z, A1.w};
#pragma unroll
    for (int e = 0; e < 8; ++e) {
      unsigned long long key =
          (((unsigned long long)__float_as_uint(lv[e])) << 32)
          | (unsigned)(tid * 8 + e);           // L >= 0: bit order == value order
      if (key > b0) { b2 = b1; b1 = b0; b0 = key; }
      else if (key > b1) { b2 = b1; b1 = key; }
      else if (key > b2) b2 = key;
    }
  }
  __syncthreads();                             // sdsh/snsh ready

  int h = 0;
  for (int round = 0; round < 3; ++round) {
    unsigned long long my = (h == 0) ? b0 : ((h == 1) ? b1 : ((h == 2) ? b2 : 0ull));
    unsigned long long w = my;
#pragma unroll
    for (int msk = 32; msk >= 1; msk >>= 1) {
      unsigned long long o = shflxor64(w, msk);
      if (o > w) w = o;
    }
    if (my == w && w != 0ull) ++h;             // unique keys (r embedded)
    if ((unsigned)(w >> 32) == 0u) continue;
    const int rwin = (int)(w & 0xFFFFFFFFull);
    const float Lsr = __uint_as_float((unsigned)(w >> 32));
    unsigned int vb = 0;
    if (lane < NK * NK) {
      const int i = lane / NK, j = lane - i * NK;
      float diff = __fsub_rn(sdsh[i], rdist[rwin * NK + j]);  // frozen chain
      float dsq  = __fmul_rn(diff, diff);
      if (dsq < 0.0101f) {
        float q    = __fdiv_rn(dsq, 0.01f);
        float temp = fmaxf(__fsub_rn(1.0f, q), 0.0f);
        if (temp > 0.0f) {
          float ub = __fmul_rn(Lsr, temp);
          float a  = L[(size_t)snsh[i] * N_PTS + ridx[rwin * NK + j]];
          float v  = __fmul_rn(ub, a);
          if (v > 0.0f) vb = __float_as_uint(v);
        }
      }
    }
#pragma unroll
    for (int msk = 32; msk >= 1; msk >>= 1) {
      unsigned int o = (unsigned)__shfl_xor((int)vb, msk);
      if (o > vb) vb = o;
    }
    if (lane == 0 && vb > 0u) atomicMax(&s_max, vb);
  }
  __syncthreads();
  if (tid == 0) lb[s] = s_max;
}

// ---------------- threshold: T' = 512th-largest lb; zero counter -------------
// count(v >= T') >= 512: each of the top-512-lb rows contributes >= 1 cell
// (its lb-achieving cell, an exact value >= T').
__global__ __launch_bounds__(1024) void thresh_kernel(
    const unsigned int* __restrict__ lb, unsigned int* __restrict__ counters) {
  __shared__ unsigned int a[N_PTS];
  const int tid = threadIdx.x;
  for (int t = tid; t < N_PTS; t += 1024) a[t] = lb[t];
  __syncthreads();
  for (int k2 = 2; k2 <= N_PTS; k2 <<= 1) {
    for (int j2 = k2 >> 1; j2 > 0; j2 >>= 1) {
      for (int e = 0; e < N_PTS / 1024; ++e) {
        int i = tid + e * 1024;
        int pj = i ^ j2;
        if (pj > i) {
          bool blk = ((i & k2) == 0);
          unsigned int x = a[i], y = a[pj];
          if (blk ? (x < y) : (x > y)) { a[i] = y; a[pj] = x; }
        }
      }
      __syncthreads();
    }
  }
  if (tid == 0) {
    counters[3] = a[TOPK - 1];
    counters[0] = 0;
  }
}

// ---------------- pass 2: collect over ALL rows, static Lsr < T' gate --------
// r6: no row-skip (required for completeness — see header). No LDS Lrow:
// each thread holds its 8 contiguous Lsr in registers (2x float4, coalesced).
// Static threshold => no volatile polling, no atomicMax warm-up. Frozen cell
// chain + div-free pre-gate identical to r5.
__global__ __launch_bounds__(256) void collect_kernel(
    const float* __restrict__ L,
    const int* __restrict__ sidx, const float* __restrict__ sdist,
    const int* __restrict__ ridx, const float* __restrict__ rdist,
    unsigned int* __restrict__ counters, uint64_t* __restrict__ cand,
    unsigned int cap) {
  __shared__ float sdsh[NK];
  __shared__ int   snsh[NK];
  const int s = blockIdx.x, tid = threadIdx.x;
  const unsigned int T = counters[3];
  const float T_f = __uint_as_float(T);
  if (tid < NK) { snsh[tid] = sidx[s * NK + tid]; sdsh[tid] = sdist[s * NK + tid]; }
  const float* __restrict__ Lg = L + (size_t)s * N_PTS;
  const float4* Lg4 = (const float4*)Lg;
  float4 A0 = Lg4[2 * tid], A1 = Lg4[2 * tid + 1];
  float lv[8] = {A0.x, A0.y, A0.z, A0.w, A1.x, A1.y, A1.z, A1.w};
  __syncthreads();

  float sd[NK];
#pragma unroll
  for (int i = 0; i < NK; ++i) sd[i] = sdsh[i];

#pragma unroll
  for (int e = 0; e < 8; ++e) {
    const float Lsr = lv[e];
    if (Lsr < T_f) continue;                             // v <= Lsr < T'
    const int r = tid * 8 + e;
    float rd[NK]; int rn[NK];
#pragma unroll
    for (int j = 0; j < NK; ++j) { rd[j] = rdist[r * NK + j]; rn[j] = ridx[r * NK + j]; }
#pragma unroll
    for (int i = 0; i < NK; ++i) {
      const float* __restrict__ Arow = L + (size_t)snsh[i] * N_PTS;
#pragma unroll
      for (int j = 0; j < NK; ++j) {
        float diff = __fsub_rn(sd[i], rd[j]);
        float dsq  = __fmul_rn(diff, diff);
        if (dsq >= 0.0101f) continue;
        float ts   = __builtin_fmaf(dsq, -99.0f, 1.0f);  // >= temp (exact)
        float ubt  = __fmul_rn(Lsr, ts);                 // >= ub >= v
        if (ubt < T_f) continue;                         // div-free pre-gate
        float q    = __fdiv_rn(dsq, 0.01f);
        float temp = fmaxf(__fsub_rn(1.0f, q), 0.0f);
        if (temp <= 0.0f) continue;
        float ub   = __fmul_rn(Lsr, temp);
        if (ub < T_f) continue;                          // v <= ub < T'
        float v = __fmul_rn(ub, Arow[rn[j]]);            // frozen chain
        unsigned int vb = __float_as_uint(v);
        if (v > 0.0f && vb >= T) {
          unsigned int pos = atomicAdd(&counters[0], 1u);
          if (pos < cap) {
            unsigned int idx = ((unsigned int)s * (unsigned int)N_PTS
                                + (unsigned int)r) * 25u
                             + (unsigned int)i * 5u + (unsigned int)j;
            cand[pos] = (((uint64_t)vb) << 32) | (uint64_t)((uint32_t)(~idx));
          }
        }
      }
    }
  }
}

// ---------------- exact top-512: byte radix-select + bitonic sort ------------
// r5: 16-way wave-split histogram + wave-0 register suffix-scan bin select.
__global__ __launch_bounds__(1024) void select_kernel(
    const uint64_t* __restrict__ cand, const unsigned int* __restrict__ counters,
    const int* __restrict__ sidx, const int* __restrict__ ridx,
    int* __restrict__ out, unsigned int cap) {
  __shared__ unsigned int h[16][257];          // wave-split histogram, padded
  __shared__ uint64_t topk[TOPK];
  __shared__ unsigned int cnt2;
  __shared__ uint64_t sh_prefix;
  __shared__ unsigned int sh_k;
  const int tid = threadIdx.x;
  const int wv = tid >> 6;
  unsigned int n = counters[0];
  if (n > cap) n = cap;
  if (tid == 0) { sh_prefix = 0; sh_k = TOPK; cnt2 = 0; }
  unsigned int* hflat = &h[0][0];

  for (int byte = 7; byte >= 0; --byte) {
    for (int t = tid; t < 16 * 257; t += 1024) hflat[t] = 0;
    __syncthreads();
    const uint64_t prefix = sh_prefix;
    const uint64_t mask = (byte == 7) ? 0ull : (~0ull << (8 * (byte + 1)));
    for (unsigned int i = tid; i < n; i += 1024) {
      uint64_t key = cand[i];
      if ((key & mask) == prefix)
        atomicAdd(&h[wv][(unsigned int)(key >> (8 * byte)) & 255u], 1u);
    }
    __syncthreads();
    if (tid < 64) {                            // wave 0: parallel bin select
      const int b0i = tid * 4;
      unsigned int c0 = 0, c1 = 0, c2 = 0, c3 = 0;
#pragma unroll
      for (int w = 0; w < 16; ++w) {
        c0 += h[w][b0i + 0]; c1 += h[w][b0i + 1];
        c2 += h[w][b0i + 2]; c3 += h[w][b0i + 3];
      }
      const unsigned int S = c0 + c1 + c2 + c3;
      unsigned int si = S;                     // inclusive suffix over lanes
#pragma unroll
      for (int off = 1; off < 64; off <<= 1) {
        unsigned int o = (unsigned)__shfl_down((int)si, off);
        si += (tid + off < 64) ? o : 0u;
      }
      const unsigned int SE = si - S;          // suffix-exclusive of this lane
      const unsigned int k = sh_k;
      const unsigned int s3 = SE + c3;
      const unsigned int s2 = s3 + c2;
      const unsigned int s1 = s2 + c1;
      const unsigned int s0 = s1 + c0;
      int b = -1; unsigned int kn = 0;
      if      (s0 >= k && s1 < k) { b = b0i + 0; kn = k - s1; }
      else if (s1 >= k && s2 < k) { b = b0i + 1; kn = k - s2; }
      else if (s2 >= k && s3 < k) { b = b0i + 2; kn = k - s3; }
      else if (s3 >= k && SE < k) { b = b0i + 3; kn = k - SE; }
      unsigned long long bal = __ballot(b >= 0);
      if (b >= 0) {
        sh_prefix = prefix | (((uint64_t)(unsigned)b) << (8 * byte));
        sh_k = kn;
      } else if (tid == 0 && bal == 0ull) {
        sh_prefix = prefix;                    // degenerate: chosen=0, k kept
      }
    }
    __syncthreads();
  }
  const uint64_t kstar = sh_prefix;

  for (int t = tid; t < TOPK; t += 1024) topk[t] = 0;
  __syncthreads();
  for (unsigned int i = tid; i < n; i += 1024) {
    uint64_t key = cand[i];
    if (key >= kstar) {
      unsigned int pos = atomicAdd(&cnt2, 1u);
      if (pos < TOPK) topk[pos] = key;
    }
  }
  __syncthreads();

  for (int k2 = 2; k2 <= TOPK; k2 <<= 1) {
    for (int j2 = k2 >> 1; j2 > 0; j2 >>= 1) {
      if (tid < TOPK) {
        int ixj = tid ^ j2;
        if (ixj > tid) {
          bool asc = ((tid & k2) == 0);
          uint64_t a = topk[tid], b = topk[ixj];
          if (asc ? (a < b) : (a > b)) { topk[tid] = b; topk[ixj] = a; }
        }
      }
      __syncthreads();
    }
  }

  if (tid < TOPK) {
    uint64_t key = topk[tid];
    unsigned int idx = ~((unsigned int)key);
    if (idx >= 104857600u) idx = 0;           // safety clamp (degenerate only)
    unsigned int s   = idx / 51200u;          // n_r*K*K = 2048*25
    unsigned int rem = idx % 51200u;
    unsigned int r   = rem / 25u;
    unsigned int sij = rem % 25u;
    out[0 * TOPK + tid] = (int)s;                       // first_node_src
    out[1 * TOPK + tid] = (int)r;                       // first_node_ref
    out[2 * TOPK + tid] = sidx[s * NK + sij / 5u];      // second_node_src
    out[3 * TOPK + tid] = ridx[r * NK + sij % 5u];      // second_node_ref
  }
}

extern "C" void kernel_launch(void* const* d_in, const int* in_sizes, int n_in,
                              void* d_out, int out_size, void* d_ws, size_t ws_size,
                              hipStream_t stream) {
  const float* src = (const float*)d_in[0];
  const float* ref = (const float*)d_in[1];
  const float* L   = (const float*)d_in[2];
  char* ws = (char*)d_ws;
  int*          sidx  = (int*)(ws + OFF_SIDX);
  float*        sdist = (float*)(ws + OFF_SDIST);
  int*          ridx  = (int*)(ws + OFF_RIDX);
  float*        rdist = (float*)(ws + OFF_RDIST);
  unsigned int* lb    = (unsigned int*)(ws + OFF_RMAX);
  unsigned int* cnts  = (unsigned int*)(ws + OFF_CNT);
  uint64_t*     cand  = (uint64_t*)(ws + OFF_CAND);
  int*          out   = (int*)d_out;

  unsigned int cap = 0;
  if (ws_size > (size_t)OFF_CAND + 8) {
    size_t c = (ws_size - (size_t)OFF_CAND) / 8;
    cap = (c > CAP_MAX) ? CAP_MAX : (unsigned int)c;
  }

  knn_kernel<<<512, 256, 0, stream>>>(src, ref, sidx, sdist, ridx, rdist);
  lowb_kernel<<<N_PTS, 256, 0, stream>>>(L, sidx, sdist, ridx, rdist, lb);
  thresh_kernel<<<1, 1024, 0, stream>>>(lb, cnts);
  collect_kernel<<<N_PTS, 256, 0, stream>>>(L, sidx, sdist, ridx, rdist, cnts, cand, cap);
  select_kernel<<<1, 1024, 0, stream>>>(cand, cnts, sidx, ridx, out, cap);
}

// Round 10
// 162.497 us; speedup vs baseline: 2.0023x; 1.0696x over previous
//
#include <hip/hip_runtime.h>
#include <stdint.h>

#define N_PTS 2048
#define NK 5
#define TOPK 512
#define CAP_MAX 262144u

// frozen arithmetic (r9-verified bit-exact vs np oracle):
//   d2 = fma(dz,dz, fma(dx,dx, dy*dy)); d = sqrt(max(d2,0))
//   q = fdiv(diff*diff, 0.01f); temp = max(1-q,0); v = (L*temp)*A
// tie rule: value desc, flat idx asc (key (vb<<32)|~idx descending)
// rejection bounds (exact under rounding, temp<=1, A<1, L>=0, A>=0):
//   v <= fmul_rn(Lsr,temp) <= Lsr
// div-free cell pre-gate (exact, RN-monotone):
//   temp <= fma(dsq,-99,1) = ts  =>  RN(Lsr*ts) >= ub >= v
// latency rule (r4): no gather-dependent value in the gate of the next gather.
// serialization rule (r5): no serial per-bin scans on one lane; no
//   clustered-key LDS atomic histograms without wave-split; wave-aggregate
//   LDS queue pushes (ballot+popc, one atomic per wave-round).
// threshold relaxation (r6): any deterministic T' <= (512th-largest lb) gives
//   a candidate superset; select's exact top-512 over a superset is
//   bit-identical. lb[s] must be an exactly-computed cell value of row s;
//   collect must scan ALL rows gated only on Lsr (no row-skip).
// launch rule (r7): no cooperative launch / grid.sync under this harness.
// anchor rule (r9): after a container failure, re-establish a known-good
//   baseline before retrying the failed structural change.
// harness floor (r9): the 256MiB workspace re-poison fill (~42us @ 6.4TB/s)
//   is inside the timed region and untouchable. Controllable budget ~130us.
// balance rule (r10): scattered survivors are compacted (LDS queue) and
//   processed cell-parallel (25 lanes/column), not 25-serial in one lane.

// ws layout (bytes):
//      0  src_ne_idx   int[10240]    (40960)
//  40960  src_ne_dist  f32[10240]    (40960)
//  81920  ref_ne_idx   int[10240]    (40960)
// 122880  ref_ne_dist  f32[10240]    (40960)
// 163840  lb           uint[2048]    (8192)   (per-row lower bound, exact cell)
// 172032  counters     uint[8]       (32)   [0]=cand_count [3]=T'
// 172064  cand         uint64[cap]
#define OFF_SIDX   0
#define OFF_SDIST  40960
#define OFF_RIDX   81920
#define OFF_RDIST  122880
#define OFF_RMAX   163840
#define OFF_CNT    172032
#define OFF_CAND   172064

__device__ __forceinline__ unsigned long long shflxor64(unsigned long long v, int mask) {
  unsigned lo = (unsigned)v, hi = (unsigned)(v >> 32);
  lo = (unsigned)__shfl_xor((int)lo, mask);
  hi = (unsigned)__shfl_xor((int)hi, mask);
  return ((unsigned long long)hi << 32) | lo;
}

// ---------------- KNN: 512 blocks, 8 points/block, 32 lanes/point ------------
__global__ __launch_bounds__(256) void knn_kernel(
    const float* __restrict__ src, const float* __restrict__ ref,
    int* __restrict__ sidx, float* __restrict__ sdist,
    int* __restrict__ ridx, float* __restrict__ rdist) {
  __shared__ float sx[N_PTS], sy[N_PTS], sz[N_PTS];
  const bool is_ref = blockIdx.x >= 256;
  const float* pts = is_ref ? ref : src;
  int*   oidx  = is_ref ? ridx : sidx;
  float* odist = is_ref ? rdist : sdist;
  const int blk = is_ref ? (blockIdx.x - 256) : blockIdx.x;

  for (int t = threadIdx.x; t < N_PTS; t += 256) {
    sx[t] = pts[3 * t + 0];
    sy[t] = pts[3 * t + 1];
    sz[t] = pts[3 * t + 2];
  }
  __syncthreads();

  const int p = blk * 8 + (threadIdx.x >> 5);
  const int u = threadIdx.x & 31;
  const float px = sx[p], py = sy[p], pz = sz[p];

  unsigned long long best[6];
#pragma unroll
  for (int k = 0; k < 6; ++k) best[k] = ~0ull;

  for (int j = u; j < N_PTS; j += 32) {
    float dx = __fsub_rn(px, sx[j]);
    float dy = __fsub_rn(py, sy[j]);
    float dz = __fsub_rn(pz, sz[j]);
    float d2 = __builtin_fmaf(dz, dz,
                 __builtin_fmaf(dx, dx, __fmul_rn(dy, dy)));
    float d = __fsqrt_rn(fmaxf(d2, 0.0f));
    unsigned long long key = (((unsigned long long)__float_as_uint(d)) << 32)
                           | (unsigned)j;
    if (key < best[5]) {
      best[5] = key;
#pragma unroll
      for (int k = 5; k >= 1; --k)
        if (best[k] < best[k - 1]) {
          unsigned long long t = best[k]; best[k] = best[k - 1]; best[k - 1] = t;
        }
    }
  }

  int h = 0;
  unsigned long long win[6];
#pragma unroll
  for (int round = 0; round < 6; ++round) {
    unsigned long long my = (h < 6) ? best[h] : ~0ull;
    unsigned long long m = my;
#pragma unroll
    for (int msk = 16; msk >= 1; msk >>= 1) {
      unsigned long long o = shflxor64(m, msk);
      if (o < m) m = o;
    }
    win[round] = m;
    if (my == m) ++h;
  }

  if (u == 0) {
#pragma unroll
    for (int m = 1; m <= NK; ++m) {     // drop win[0] == self (d = 0)
      oidx[p * NK + m - 1]  = (int)(win[m] & 0xFFFFFFFFull);
      odist[p * NK + m - 1] = __uint_as_float((unsigned)(win[m] >> 32));
    }
  }
}

// ---------------- pass 1: per-row LOWER BOUND (seed only, no exact max) ------
// r9-verified: per-wave top-3 Lsr columns, each evaluated exactly with the
// FROZEN chain on 25 lanes. lb[s] = max of evaluated cell values (or 0).
__global__ __launch_bounds__(256) void lowb_kernel(
    const float* __restrict__ L,
    const int* __restrict__ sidx, const float* __restrict__ sdist,
    const int* __restrict__ ridx, const float* __restrict__ rdist,
    unsigned int* __restrict__ lb) {
  __shared__ float sdsh[NK];
  __shared__ int   snsh[NK];
  __shared__ unsigned int s_max;
  const int s = blockIdx.x, tid = threadIdx.x;
  const int lane = tid & 63;
  if (tid < NK) { snsh[tid] = sidx[s * NK + tid]; sdsh[tid] = sdist[s * NK + tid]; }
  if (tid == 0) s_max = 0;
  const float* __restrict__ Lg = L + (size_t)s * N_PTS;

  // per-thread top-3 over its 8 contiguous columns (2x float4, coalesced)
  unsigned long long b0 = 0ull, b1 = 0ull, b2 = 0ull;
  {
    const float4* Lg4 = (const float4*)Lg;
    float4 A0 = Lg4[2 * tid], A1 = Lg4[2 * tid + 1];
    float lv[8] = {A0.x, A0.y, A0.z, A0.w, A1.x, A1.y, A1.z, A1.w};
#pragma unroll
    for (int e = 0; e < 8; ++e) {
      unsigned long long key =
          (((unsigned long long)__float_as_uint(lv[e])) << 32)
          | (unsigned)(tid * 8 + e);           // L >= 0: bit order == value order
      if (key > b0) { b2 = b1; b1 = b0; b0 = key; }
      else if (key > b1) { b2 = b1; b1 = key; }
      else if (key > b2) b2 = key;
    }
  }
  __syncthreads();                             // sdsh/snsh ready

  int h = 0;
  for (int round = 0; round < 3; ++round) {
    unsigned long long my = (h == 0) ? b0 : ((h == 1) ? b1 : ((h == 2) ? b2 : 0ull));
    unsigned long long w = my;
#pragma unroll
    for (int msk = 32; msk >= 1; msk >>= 1) {
      unsigned long long o = shflxor64(w, msk);
      if (o > w) w = o;
    }
    if (my == w && w != 0ull) ++h;             // unique keys (r embedded)
    if ((unsigned)(w >> 32) == 0u) continue;
    const int rwin = (int)(w & 0xFFFFFFFFull);
    const float Lsr = __uint_as_float((unsigned)(w >> 32));
    unsigned int vb = 0;
    if (lane < NK * NK) {
      const int i = lane / NK, j = lane - i * NK;
      float diff = __fsub_rn(sdsh[i], rdist[rwin * NK + j]);  // frozen chain
      float dsq  = __fmul_rn(diff, diff);
      if (dsq < 0.0101f) {
        float q    = __fdiv_rn(dsq, 0.01f);
        float temp = fmaxf(__fsub_rn(1.0f, q), 0.0f);
        if (temp > 0.0f) {
          float ub = __fmul_rn(Lsr, temp);
          float a  = L[(size_t)snsh[i] * N_PTS + ridx[rwin * NK + j]];
          float v  = __fmul_rn(ub, a);
          if (v > 0.0f) vb = __float_as_uint(v);
        }
      }
    }
#pragma unroll
    for (int msk = 32; msk >= 1; msk >>= 1) {
      unsigned int o = (unsigned)__shfl_xor((int)vb, msk);
      if (o > vb) vb = o;
    }
    if (lane == 0 && vb > 0u) atomicMax(&s_max, vb);
  }
  __syncthreads();
  if (tid == 0) lb[s] = s_max;
}

// ---------------- threshold: T' = 512th-largest lb; zero counter -------------
__global__ __launch_bounds__(1024) void thresh_kernel(
    const unsigned int* __restrict__ lb, unsigned int* __restrict__ counters) {
  __shared__ unsigned int a[N_PTS];
  const int tid = threadIdx.x;
  for (int t = tid; t < N_PTS; t += 1024) a[t] = lb[t];
  __syncthreads();
  for (int k2 = 2; k2 <= N_PTS; k2 <<= 1) {
    for (int j2 = k2 >> 1; j2 > 0; j2 >>= 1) {
      for (int e = 0; e < N_PTS / 1024; ++e) {
        int i = tid + e * 1024;
        int pj = i ^ j2;
        if (pj > i) {
          bool blk = ((i & k2) == 0);
          unsigned int x = a[i], y = a[pj];
          if (blk ? (x < y) : (x > y)) { a[i] = y; a[pj] = x; }
        }
      }
      __syncthreads();
    }
  }
  if (tid == 0) {
    counters[3] = a[TOPK - 1];
    counters[0] = 0;
  }
}

// ---------------- pass 2: collect, compacted + cell-parallel (r10) -----------
// Phase A: threads scan their 8 register-held L-values; survivors (Lsr>=T')
//   pushed (r,Lsr) into an LDS queue via wave-aggregated atomics (one
//   atomicAdd per wave per ballot round).
// Phase B: 8 x 32-lane groups; group g takes queue entry base+g; lane l<25
//   computes cell (i,j)=(l/5,l%5) with the FROZEN chain + gates => all
//   fdiv/gather chains of a column run in parallel lanes. Emission content
//   identical to r9 (cand order differs; select's key is a total order =>
//   output bit-identical). No barriers in divergent regions.
__global__ __launch_bounds__(256) void collect_kernel(
    const float* __restrict__ L,
    const int* __restrict__ sidx, const float* __restrict__ sdist,
    const int* __restrict__ ridx, const float* __restrict__ rdist,
    unsigned int* __restrict__ counters, uint64_t* __restrict__ cand,
    unsigned int cap) {
  __shared__ float sdsh[NK];
  __shared__ int   snsh[NK];
  __shared__ int   q_r[N_PTS];
  __shared__ float q_L[N_PTS];
  __shared__ unsigned int qn;
  const int s = blockIdx.x, tid = threadIdx.x;
  const int lane = tid & 63;
  const unsigned int T = counters[3];
  const float T_f = __uint_as_float(T);
  if (tid < NK) { snsh[tid] = sidx[s * NK + tid]; sdsh[tid] = sdist[s * NK + tid]; }
  if (tid == 0) qn = 0;
  const float4* Lg4 = (const float4*)(L + (size_t)s * N_PTS);
  float4 A0 = Lg4[2 * tid], A1 = Lg4[2 * tid + 1];
  float lv[8] = {A0.x, A0.y, A0.z, A0.w, A1.x, A1.y, A1.z, A1.w};
  __syncthreads();                             // qn=0, sdsh/snsh visible

  // ---- phase A: wave-aggregated survivor push ----
#pragma unroll
  for (int e = 0; e < 8; ++e) {
    const float Lsr = lv[e];
    const bool surv = (Lsr >= T_f);            // v <= Lsr < T' => reject rest
    unsigned long long mask = __ballot(surv);
    if (surv) {
      const int leader = __ffsll((long long)mask) - 1;
      unsigned int base = 0;
      if (lane == leader) base = atomicAdd(&qn, (unsigned int)__popcll(mask));
      base = (unsigned int)__shfl((int)base, leader);
      const unsigned int off =
          (unsigned int)__popcll(mask & ((1ull << lane) - 1ull));
      q_r[base + off] = tid * 8 + e;           // base+off < 2048 always
      q_L[base + off] = Lsr;
    }
  }
  __syncthreads();
  const unsigned int nq = qn;

  // ---- phase B: cell-parallel processing, 8 groups x 32 lanes ----
  const int g = tid >> 5, l32 = tid & 31;
  const bool cell = (l32 < NK * NK);
  const int ci = cell ? (l32 / NK) : 0;
  const int cj = cell ? (l32 - ci * NK) : 0;
  const float sd_i = sdsh[ci];
  const float* __restrict__ Arow = L + (size_t)snsh[ci] * N_PTS;

  for (unsigned int base = 0; base < nq; base += 8) {
    const unsigned int qi = base + (unsigned int)g;
    if (qi >= nq) break;                       // group-uniform; no barriers here
    const int r = q_r[qi];
    const float Lsr = q_L[qi];
    if (cell) {
      float rdv  = rdist[r * NK + cj];
      float diff = __fsub_rn(sd_i, rdv);
      float dsq  = __fmul_rn(diff, diff);
      if (dsq < 0.0101f) {                               // else temp provably 0
        float ts  = __builtin_fmaf(dsq, -99.0f, 1.0f);   // >= temp (exact)
        float ubt = __fmul_rn(Lsr, ts);                  // >= ub >= v
        if (ubt >= T_f) {                                // div-free pre-gate
          float q    = __fdiv_rn(dsq, 0.01f);
          float temp = fmaxf(__fsub_rn(1.0f, q), 0.0f);
          if (temp > 0.0f) {
            float ub = __fmul_rn(Lsr, temp);
            if (ub >= T_f) {                             // v <= ub < T' reject
              int   rn = ridx[r * NK + cj];
              float v  = __fmul_rn(ub, Arow[rn]);        // frozen chain
              unsigned int vb = __float_as_uint(v);
              if (v > 0.0f && vb >= T) {
                unsigned int pos = atomicAdd(&counters[0], 1u);
                if (pos < cap) {
                  unsigned int idx = ((unsigned int)s * (unsigned int)N_PTS
                                      + (unsigned int)r) * 25u
                                   + (unsigned int)ci * 5u + (unsigned int)cj;
                  cand[pos] = (((uint64_t)vb) << 32)
                            | (uint64_t)((uint32_t)(~idx));
                }
              }
            }
          }
        }
      }
    }
  }
}

// ---------------- exact top-512: byte radix-select + bitonic sort ------------
// r5: 16-way wave-split histogram + wave-0 register suffix-scan bin select.
__global__ __launch_bounds__(1024) void select_kernel(
    const uint64_t* __restrict__ cand, const unsigned int* __restrict__ counters,
    const int* __restrict__ sidx, const int* __restrict__ ridx,
    int* __restrict__ out, unsigned int cap) {
  __shared__ unsigned int h[16][257];          // wave-split histogram, padded
  __shared__ uint64_t topk[TOPK];
  __shared__ unsigned int cnt2;
  __shared__ uint64_t sh_prefix;
  __shared__ unsigned int sh_k;
  const int tid = threadIdx.x;
  const int wv = tid >> 6;
  unsigned int n = counters[0];
  if (n > cap) n = cap;
  if (tid == 0) { sh_prefix = 0; sh_k = TOPK; cnt2 = 0; }
  unsigned int* hflat = &h[0][0];

  for (int byte = 7; byte >= 0; --byte) {
    for (int t = tid; t < 16 * 257; t += 1024) hflat[t] = 0;
    __syncthreads();
    const uint64_t prefix = sh_prefix;
    const uint64_t mask = (byte == 7) ? 0ull : (~0ull << (8 * (byte + 1)));
    for (unsigned int i = tid; i < n; i += 1024) {
      uint64_t key = cand[i];
      if ((key & mask) == prefix)
        atomicAdd(&h[wv][(unsigned int)(key >> (8 * byte)) & 255u], 1u);
    }
    __syncthreads();
    if (tid < 64) {                            // wave 0: parallel bin select
      const int b0i = tid * 4;
      unsigned int c0 = 0, c1 = 0, c2 = 0, c3 = 0;
#pragma unroll
      for (int w = 0; w < 16; ++w) {
        c0 += h[w][b0i + 0]; c1 += h[w][b0i + 1];
        c2 += h[w][b0i + 2]; c3 += h[w][b0i + 3];
      }
      const unsigned int S = c0 + c1 + c2 + c3;
      unsigned int si = S;                     // inclusive suffix over lanes
#pragma unroll
      for (int off = 1; off < 64; off <<= 1) {
        unsigned int o = (unsigned)__shfl_down((int)si, off);
        si += (tid + off < 64) ? o : 0u;
      }
      const unsigned int SE = si - S;          // suffix-exclusive of this lane
      const unsigned int k = sh_k;
      const unsigned int s3 = SE + c3;
      const unsigned int s2 = s3 + c2;
      const unsigned int s1 = s2 + c1;
      const unsigned int s0 = s1 + c0;
      int b = -1; unsigned int kn = 0;
      if      (s0 >= k && s1 < k) { b = b0i + 0; kn = k - s1; }
      else if (s1 >= k && s2 < k) { b = b0i + 1; kn = k - s2; }
      else if (s2 >= k && s3 < k) { b = b0i + 2; kn = k - s3; }
      else if (s3 >= k && SE < k) { b = b0i + 3; kn = k - SE; }
      unsigned long long bal = __ballot(b >= 0);
      if (b >= 0) {
        sh_prefix = prefix | (((uint64_t)(unsigned)b) << (8 * byte));
        sh_k = kn;
      } else if (tid == 0 && bal == 0ull) {
        sh_prefix = prefix;                    // degenerate: chosen=0, k kept
      }
    }
    __syncthreads();
  }
  const uint64_t kstar = sh_prefix;

  for (int t = tid; t < TOPK; t += 1024) topk[t] = 0;
  __syncthreads();
  for (unsigned int i = tid; i < n; i += 1024) {
    uint64_t key = cand[i];
    if (key >= kstar) {
      unsigned int pos = atomicAdd(&cnt2, 1u);
      if (pos < TOPK) topk[pos] = key;
    }
  }
  __syncthreads();

  for (int k2 = 2; k2 <= TOPK; k2 <<= 1) {
    for (int j2 = k2 >> 1; j2 > 0; j2 >>= 1) {
      if (tid < TOPK) {
        int ixj = tid ^ j2;
        if (ixj > tid) {
          bool asc = ((tid & k2) == 0);
          uint64_t a = topk[tid], b = topk[ixj];
          if (asc ? (a < b) : (a > b)) { topk[tid] = b; topk[ixj] = a; }
        }
      }
      __syncthreads();
    }
  }

  if (tid < TOPK) {
    uint64_t key = topk[tid];
    unsigned int idx = ~((unsigned int)key);
    if (idx >= 104857600u) idx = 0;           // safety clamp (degenerate only)
    unsigned int s   = idx / 51200u;          // n_r*K*K = 2048*25
    unsigned int rem = idx % 51200u;
    unsigned int r   = rem / 25u;
    unsigned int sij = rem % 25u;
    out[0 * TOPK + tid] = (int)s;                       // first_node_src
    out[1 * TOPK + tid] = (int)r;                       // first_node_ref
    out[2 * TOPK + tid] = sidx[s * NK + sij / 5u];      // second_node_src
    out[3 * TOPK + tid] = ridx[r * NK + sij % 5u];      // second_node_ref
  }
}

extern "C" void kernel_launch(void* const* d_in, const int* in_sizes, int n_in,
                              void* d_out, int out_size, void* d_ws, size_t ws_size,
                              hipStream_t stream) {
  const float* src = (const float*)d_in[0];
  const float* ref = (const float*)d_in[1];
  const float* L   = (const float*)d_in[2];
  char* ws = (char*)d_ws;
  int*          sidx  = (int*)(ws + OFF_SIDX);
  float*        sdist = (float*)(ws + OFF_SDIST);
  int*          ridx  = (int*)(ws + OFF_RIDX);
  float*        rdist = (float*)(ws + OFF_RDIST);
  unsigned int* lb    = (unsigned int*)(ws + OFF_RMAX);
  unsigned int* cnts  = (unsigned int*)(ws + OFF_CNT);
  uint64_t*     cand  = (uint64_t*)(ws + OFF_CAND);
  int*          out   = (int*)d_out;

  unsigned int cap = 0;
  if (ws_size > (size_t)OFF_CAND + 8) {
    size_t c = (ws_size - (size_t)OFF_CAND) / 8;
    cap = (c > CAP_MAX) ? CAP_MAX : (unsigned int)c;
  }

  knn_kernel<<<512, 256, 0, stream>>>(src, ref, sidx, sdist, ridx, rdist);
  lowb_kernel<<<N_PTS, 256, 0, stream>>>(L, sidx, sdist, ridx, rdist, lb);
  thresh_kernel<<<1, 1024, 0, stream>>>(lb, cnts);
  collect_kernel<<<N_PTS, 256, 0, stream>>>(L, sidx, sdist, ridx, rdist, cnts, cand, cap);
  select_kernel<<<1, 1024, 0, stream>>>(cand, cnts, sidx, ridx, out, cap);
}